// Round 1
// baseline (4169.637 us; speedup 1.0000x reference)
//
#include <hip/hip_runtime.h>
#include <math.h>

#define NN 50000
#define NE 600000
#define CC 128
#define NL 3

// ---------------- transpose [384][128] -> [128][384] ----------------
__global__ __launch_bounds__(256) void k_transpose_w(const float* __restrict__ w,
                                                     float* __restrict__ wt) {
    int tid = blockIdx.x * 256 + threadIdx.x;   // 49152 total
    int j = tid >> 7;     // 0..383
    int k = tid & 127;    // 0..127
    wt[k * 384 + j] = w[j * 128 + k];
}

// ---------------- m = h @ W   ([N,128] x [128,128]) ----------------
__global__ __launch_bounds__(256) void k_conv(const float* __restrict__ h,
                                              const float* __restrict__ W,
                                              float* __restrict__ m) {
    __shared__ float As[16][128];
    int t = threadIdx.x;
    int row0 = blockIdx.x * 16;
    {
        const float4* h4 = (const float4*)(h + (size_t)row0 * CC);
        float4* As4 = (float4*)As;
        As4[t] = h4[t];
        As4[256 + t] = h4[256 + t];
    }
    __syncthreads();
    int ct = t & 31, rt = t >> 5;           // cols ct*4..+4, rows rt*2+{0,1}
    const float* A0 = As[rt * 2];
    const float* A1 = As[rt * 2 + 1];
    const float4* W4 = (const float4*)W;    // W[k][c], row k = 32 float4
    float acc0[4] = {0.f, 0.f, 0.f, 0.f};
    float acc1[4] = {0.f, 0.f, 0.f, 0.f};
    for (int k = 0; k < 128; k++) {
        float a0 = A0[k], a1 = A1[k];
        float w[4];
        *(float4*)w = W4[k * 32 + ct];
#pragma unroll
        for (int j = 0; j < 4; j++) {
            acc0[j] += a0 * w[j];
            acc1[j] += a1 * w[j];
        }
    }
    float4* m4 = (float4*)(m + (size_t)row0 * CC);
    m4[(rt * 2) * 32 + ct] = *(float4*)acc0;
    m4[(rt * 2 + 1) * 32 + ct] = *(float4*)acc1;
}

// ---------------- agg[dst] += w * m[src]  (one 32-lane group per edge) ----------------
__global__ __launch_bounds__(256) void k_scatter(const int* __restrict__ src,
                                                 const int* __restrict__ dst,
                                                 const float* __restrict__ ew,
                                                 const float* __restrict__ m,
                                                 float* __restrict__ agg) {
    int tid = blockIdx.x * 256 + threadIdx.x;   // E*32 threads
    int e = tid >> 5, q = tid & 31;
    int s = src[e], d = dst[e];
    float w = ew[e];
    float4 v = ((const float4*)m)[(size_t)s * 32 + q];
    float* ap = agg + (size_t)d * CC + q * 4;
    atomicAdd(ap + 0, w * v.x);
    atomicAdd(ap + 1, w * v.y);
    atomicAdd(ap + 2, w * v.z);
    atomicAdd(ap + 3, w * v.w);
}

// ---------------- fused GRU cell: h = GRU(agg, h) (in place) ----------------
__global__ __launch_bounds__(256) void k_gru(const float* __restrict__ agg,
                                             float* __restrict__ h,
                                             const float* __restrict__ wih_t,
                                             const float* __restrict__ whh_t,
                                             const float* __restrict__ b_ih,
                                             const float* __restrict__ b_hh) {
    __shared__ float As[16][128];
    __shared__ float Hs[16][128];
    int t = threadIdx.x;
    int row0 = blockIdx.x * 16;
    {
        const float4* a4 = (const float4*)(agg + (size_t)row0 * CC);
        const float4* h4 = (const float4*)(h + (size_t)row0 * CC);
        float4* As4 = (float4*)As;
        float4* Hs4 = (float4*)Hs;
        As4[t] = a4[t];
        As4[256 + t] = a4[256 + t];
        Hs4[t] = h4[t];
        Hs4[256 + t] = h4[256 + t];
    }
    __syncthreads();
    int ct = t & 31, rt = t >> 5;
    const float* A0 = As[rt * 2];
    const float* A1 = As[rt * 2 + 1];
    const float* H0 = Hs[rt * 2];
    const float* H1 = Hs[rt * 2 + 1];
    const float4* Wx4 = (const float4*)wih_t;   // [128][384], row k = 96 float4
    const float4* Wh4 = (const float4*)whh_t;
    float acc[2][6][4];
#pragma unroll
    for (int i = 0; i < 2; i++)
#pragma unroll
        for (int g = 0; g < 6; g++)
#pragma unroll
            for (int j = 0; j < 4; j++) acc[i][g][j] = 0.f;

    for (int k = 0; k < 128; k++) {
        float a0 = A0[k], a1 = A1[k], h0 = H0[k], h1 = H1[k];
#pragma unroll
        for (int g = 0; g < 3; g++) {
            float wx[4], wh[4];
            *(float4*)wx = Wx4[k * 96 + g * 32 + ct];
            *(float4*)wh = Wh4[k * 96 + g * 32 + ct];
#pragma unroll
            for (int j = 0; j < 4; j++) {
                acc[0][g][j] += a0 * wx[j];
                acc[1][g][j] += a1 * wx[j];
                acc[0][3 + g][j] += h0 * wh[j];
                acc[1][3 + g][j] += h1 * wh[j];
            }
        }
    }
    float bir[4], biz[4], bin_[4], bhr[4], bhz[4], bhn[4];
    *(float4*)bir = ((const float4*)b_ih)[ct];
    *(float4*)biz = ((const float4*)b_ih)[32 + ct];
    *(float4*)bin_ = ((const float4*)b_ih)[64 + ct];
    *(float4*)bhr = ((const float4*)b_hh)[ct];
    *(float4*)bhz = ((const float4*)b_hh)[32 + ct];
    *(float4*)bhn = ((const float4*)b_hh)[64 + ct];
#pragma unroll
    for (int i = 0; i < 2; i++) {
        int lr = rt * 2 + i;
        float hv[4];
        *(float4*)hv = *(const float4*)&Hs[lr][ct * 4];
        float outv[4];
#pragma unroll
        for (int j = 0; j < 4; j++) {
            float xr = acc[i][0][j] + bir[j];
            float xz = acc[i][1][j] + biz[j];
            float xn = acc[i][2][j] + bin_[j];
            float hr = acc[i][3][j] + bhr[j];
            float hz = acc[i][4][j] + bhz[j];
            float hn = acc[i][5][j] + bhn[j];
            float r = 1.f / (1.f + expf(-(xr + hr)));
            float z = 1.f / (1.f + expf(-(xz + hz)));
            float n = tanhf(xn + r * hn);
            outv[j] = (1.f - z) * n + z * hv[j];
        }
        *(float4*)&h[(size_t)(row0 + lr) * CC + ct * 4] = *(float4*)outv;
    }
}

// ---------------- fused MLP + log_softmax ----------------
__global__ __launch_bounds__(256) void k_mlp(const float* __restrict__ h,
                                             const float* __restrict__ w0, const float* __restrict__ b0,
                                             const float* __restrict__ w1, const float* __restrict__ b1,
                                             const float* __restrict__ w2, const float* __restrict__ b2,
                                             const float* __restrict__ w3, const float* __restrict__ b3,
                                             float* __restrict__ out) {
    __shared__ float w0s[32 * 128];
    __shared__ float w1s[32 * 32];
    __shared__ float w2s[32 * 32];
    __shared__ float w3s[7 * 32];
    __shared__ float bs[104];            // b0[0:32] b1[32:64] b2[64:96] b3[96:103]
    __shared__ float hs[256][33];        // +1 pad: conflict-free per-row reads
    int t = threadIdx.x;
    for (int i = t; i < 4096; i += 256) w0s[i] = w0[i];
    for (int i = t; i < 1024; i += 256) { w1s[i] = w1[i]; w2s[i] = w2[i]; }
    for (int i = t; i < 224; i += 256) w3s[i] = w3[i];
    if (t < 32) { bs[t] = b0[t]; bs[32 + t] = b1[t]; bs[64 + t] = b2[t]; }
    if (t < 7) bs[96 + t] = b3[t];

    int row = blockIdx.x * 256 + t;
    float acc0[32];
#pragma unroll
    for (int j = 0; j < 32; j++) acc0[j] = 0.f;

    for (int k0 = 0; k0 < 128; k0 += 32) {
        __syncthreads();
#pragma unroll
        for (int it = 0; it < 8; it++) {
            int idx = it * 256 + t;
            int r = idx >> 3, cq = idx & 7;
            int grow = blockIdx.x * 256 + r;
            float4 v = make_float4(0.f, 0.f, 0.f, 0.f);
            if (grow < NN) v = ((const float4*)h)[(size_t)grow * 32 + (k0 >> 2) + cq];
            hs[r][cq * 4 + 0] = v.x;
            hs[r][cq * 4 + 1] = v.y;
            hs[r][cq * 4 + 2] = v.z;
            hs[r][cq * 4 + 3] = v.w;
        }
        __syncthreads();
        for (int kk = 0; kk < 32; kk++) {
            float xk = hs[t][kk];
#pragma unroll
            for (int j = 0; j < 32; j++) acc0[j] += xk * w0s[j * 128 + k0 + kk];
        }
    }
    float v0[32];
#pragma unroll
    for (int j = 0; j < 32; j++) v0[j] = tanhf(acc0[j] + bs[j]);
    float v1[32];
#pragma unroll
    for (int j = 0; j < 32; j++) {
        float s = bs[32 + j];
#pragma unroll
        for (int k = 0; k < 32; k++) s += w1s[j * 32 + k] * v0[k];
        v1[j] = tanhf(s);
    }
    float v2[32];
#pragma unroll
    for (int j = 0; j < 32; j++) {
        float s = bs[64 + j];
#pragma unroll
        for (int k = 0; k < 32; k++) s += w2s[j * 32 + k] * v1[k];
        v2[j] = tanhf(s);
    }
    float y3[7];
#pragma unroll
    for (int j = 0; j < 7; j++) {
        float s = bs[96 + j];
#pragma unroll
        for (int k = 0; k < 32; k++) s += w3s[j * 32 + k] * v2[k];
        y3[j] = s;
    }
    float mx = y3[0];
#pragma unroll
    for (int j = 1; j < 7; j++) mx = fmaxf(mx, y3[j]);
    float se = 0.f;
#pragma unroll
    for (int j = 0; j < 7; j++) se += expf(y3[j] - mx);
    float lse = mx + logf(se);
    if (row < NN) {
#pragma unroll
        for (int j = 0; j < 7; j++) out[(size_t)row * 7 + j] = y3[j] - lse;
    }
}

extern "C" void kernel_launch(void* const* d_in, const int* in_sizes, int n_in,
                              void* d_out, int out_size, void* d_ws, size_t ws_size,
                              hipStream_t stream) {
    const float* x   = (const float*)d_in[0];
    const int*   ei  = (const int*)d_in[1];     // [2, E]
    const float* ew  = (const float*)d_in[2];
    const float* cw  = (const float*)d_in[3];   // [L,128,128]
    const float* wih = (const float*)d_in[4];   // [384,128]
    const float* whh = (const float*)d_in[5];
    const float* bih = (const float*)d_in[6];
    const float* bhh = (const float*)d_in[7];
    const float* w0 = (const float*)d_in[8];
    const float* b0 = (const float*)d_in[9];
    const float* w1 = (const float*)d_in[10];
    const float* b1 = (const float*)d_in[11];
    const float* w2 = (const float*)d_in[12];
    const float* b2 = (const float*)d_in[13];
    const float* w3 = (const float*)d_in[14];
    const float* b3 = (const float*)d_in[15];
    float* out = (float*)d_out;

    float* h     = (float*)d_ws;                 // N*C
    float* m     = h + (size_t)NN * CC;          // N*C
    float* agg   = m + (size_t)NN * CC;          // N*C
    float* wih_t = agg + (size_t)NN * CC;        // 128*384
    float* whh_t = wih_t + 3 * CC * CC;          // 128*384

    hipMemcpyAsync(h, x, (size_t)NN * CC * sizeof(float), hipMemcpyDeviceToDevice, stream);
    k_transpose_w<<<192, 256, 0, stream>>>(wih, wih_t);
    k_transpose_w<<<192, 256, 0, stream>>>(whh, whh_t);

    for (int l = 0; l < NL; l++) {
        k_conv<<<NN / 16, 256, 0, stream>>>(h, cw + (size_t)l * CC * CC, m);
        hipMemsetAsync(agg, 0, (size_t)NN * CC * sizeof(float), stream);
        k_scatter<<<(NE * 32) / 256, 256, 0, stream>>>(ei, ei + NE, ew, m, agg);
        k_gru<<<NN / 16, 256, 0, stream>>>(agg, h, wih_t, whh_t, bih, bhh);
    }
    k_mlp<<<(NN + 255) / 256, 256, 0, stream>>>(h, w0, b0, w1, b1, w2, b2, w3, b3, out);
}

// Round 2
// 1452.518 us; speedup vs baseline: 2.8706x; 2.8706x over previous
//
#include <hip/hip_runtime.h>
#include <math.h>

#define NN 50000
#define NE 600000
#define CC 128
#define NL 3

// ---------------- transpose [384][128] -> [128][384] ----------------
__global__ __launch_bounds__(256) void k_transpose_w(const float* __restrict__ w,
                                                     float* __restrict__ wt) {
    int tid = blockIdx.x * 256 + threadIdx.x;   // 49152 total
    int j = tid >> 7;     // 0..383
    int k = tid & 127;    // 0..127
    wt[k * 384 + j] = w[j * 128 + k];
}

// ---------------- CSR build: histogram, scan, fill ----------------
__global__ __launch_bounds__(256) void k_count(const int* __restrict__ dst,
                                               int* __restrict__ deg) {
    int e = blockIdx.x * 256 + threadIdx.x;
    if (e < NE) atomicAdd(&deg[dst[e]], 1);
}

__global__ __launch_bounds__(1024) void k_scan(const int* __restrict__ deg,
                                               int* __restrict__ off) {
    __shared__ int part[1024];
    int t = threadIdx.x;
    const int CH = (NN + 1023) / 1024;   // 49
    int base = t * CH;
    int s = 0;
    for (int i = 0; i < CH; i++) {
        int idx = base + i;
        if (idx < NN) s += deg[idx];
    }
    part[t] = s;
    __syncthreads();
    for (int ofs = 1; ofs < 1024; ofs <<= 1) {
        int v = (t >= ofs) ? part[t - ofs] : 0;
        __syncthreads();
        part[t] += v;
        __syncthreads();
    }
    int run = (t == 0) ? 0 : part[t - 1];
    for (int i = 0; i < CH; i++) {
        int idx = base + i;
        if (idx < NN) { off[idx] = run; run += deg[idx]; }
    }
    if (t == 1023) off[NN] = part[1023];
}

__global__ __launch_bounds__(256) void k_fill(const int* __restrict__ src,
                                              const int* __restrict__ dst,
                                              const float* __restrict__ ew,
                                              int* __restrict__ cursor,
                                              int* __restrict__ e_src,
                                              float* __restrict__ e_w) {
    int e = blockIdx.x * 256 + threadIdx.x;
    if (e >= NE) return;
    int d = dst[e];
    int p = atomicAdd(&cursor[d], 1);
    e_src[p] = src[e];
    e_w[p] = ew[e];
}

// ---------------- m = h @ W   ([N,128] x [128,128]) ----------------
__global__ __launch_bounds__(256) void k_conv(const float* __restrict__ h,
                                              const float* __restrict__ W,
                                              float* __restrict__ m) {
    __shared__ float As[16][128];
    int t = threadIdx.x;
    int row0 = blockIdx.x * 16;
    {
        const float4* h4 = (const float4*)(h + (size_t)row0 * CC);
        float4* As4 = (float4*)As;
        As4[t] = h4[t];
        As4[256 + t] = h4[256 + t];
    }
    __syncthreads();
    int ct = t & 31, rt = t >> 5;           // cols ct*4..+4, rows rt*2+{0,1}
    const float* A0 = As[rt * 2];
    const float* A1 = As[rt * 2 + 1];
    const float4* W4 = (const float4*)W;    // W[k][c], row k = 32 float4
    float acc0[4] = {0.f, 0.f, 0.f, 0.f};
    float acc1[4] = {0.f, 0.f, 0.f, 0.f};
    for (int k = 0; k < 128; k++) {
        float a0 = A0[k], a1 = A1[k];
        float w[4];
        *(float4*)w = W4[k * 32 + ct];
#pragma unroll
        for (int j = 0; j < 4; j++) {
            acc0[j] += a0 * w[j];
            acc1[j] += a1 * w[j];
        }
    }
    float4* m4 = (float4*)(m + (size_t)row0 * CC);
    m4[(rt * 2) * 32 + ct] = *(float4*)acc0;
    m4[(rt * 2 + 1) * 32 + ct] = *(float4*)acc1;
}

// ---------------- agg[n] = sum_{e in CSR[n]} w_e * m[src_e]  (wave per node) ----------------
__global__ __launch_bounds__(256) void k_agg(const int* __restrict__ off,
                                             const int* __restrict__ e_src,
                                             const float* __restrict__ e_w,
                                             const float* __restrict__ m,
                                             float* __restrict__ agg) {
    int node = blockIdx.x * 4 + (threadIdx.x >> 6);
    int lane = threadIdx.x & 63;
    if (node >= NN) return;
    int b = off[node], e = off[node + 1];
    const float2* m2 = (const float2*)m;
    float ax = 0.f, ay = 0.f;
    for (int i = b; i < e; i++) {
        int s = e_src[i];
        float w = e_w[i];
        float2 v = m2[(size_t)s * 64 + lane];
        ax += w * v.x;
        ay += w * v.y;
    }
    float2 r; r.x = ax; r.y = ay;
    ((float2*)agg)[(size_t)node * 64 + lane] = r;
}

// ---------------- fused GRU cell: h = GRU(agg, h) (in place) ----------------
__global__ __launch_bounds__(256) void k_gru(const float* __restrict__ agg,
                                             float* __restrict__ h,
                                             const float* __restrict__ wih_t,
                                             const float* __restrict__ whh_t,
                                             const float* __restrict__ b_ih,
                                             const float* __restrict__ b_hh) {
    __shared__ float As[16][128];
    __shared__ float Hs[16][128];
    int t = threadIdx.x;
    int row0 = blockIdx.x * 16;
    {
        const float4* a4 = (const float4*)(agg + (size_t)row0 * CC);
        const float4* h4 = (const float4*)(h + (size_t)row0 * CC);
        float4* As4 = (float4*)As;
        float4* Hs4 = (float4*)Hs;
        As4[t] = a4[t];
        As4[256 + t] = a4[256 + t];
        Hs4[t] = h4[t];
        Hs4[256 + t] = h4[256 + t];
    }
    __syncthreads();
    int ct = t & 31, rt = t >> 5;
    const float* A0 = As[rt * 2];
    const float* A1 = As[rt * 2 + 1];
    const float* H0 = Hs[rt * 2];
    const float* H1 = Hs[rt * 2 + 1];
    const float4* Wx4 = (const float4*)wih_t;   // [128][384], row k = 96 float4
    const float4* Wh4 = (const float4*)whh_t;
    float acc[2][6][4];
#pragma unroll
    for (int i = 0; i < 2; i++)
#pragma unroll
        for (int g = 0; g < 6; g++)
#pragma unroll
            for (int j = 0; j < 4; j++) acc[i][g][j] = 0.f;

    for (int k = 0; k < 128; k++) {
        float a0 = A0[k], a1 = A1[k], h0 = H0[k], h1 = H1[k];
#pragma unroll
        for (int g = 0; g < 3; g++) {
            float wx[4], wh[4];
            *(float4*)wx = Wx4[k * 96 + g * 32 + ct];
            *(float4*)wh = Wh4[k * 96 + g * 32 + ct];
#pragma unroll
            for (int j = 0; j < 4; j++) {
                acc[0][g][j] += a0 * wx[j];
                acc[1][g][j] += a1 * wx[j];
                acc[0][3 + g][j] += h0 * wh[j];
                acc[1][3 + g][j] += h1 * wh[j];
            }
        }
    }
    float bir[4], biz[4], bin_[4], bhr[4], bhz[4], bhn[4];
    *(float4*)bir = ((const float4*)b_ih)[ct];
    *(float4*)biz = ((const float4*)b_ih)[32 + ct];
    *(float4*)bin_ = ((const float4*)b_ih)[64 + ct];
    *(float4*)bhr = ((const float4*)b_hh)[ct];
    *(float4*)bhz = ((const float4*)b_hh)[32 + ct];
    *(float4*)bhn = ((const float4*)b_hh)[64 + ct];
#pragma unroll
    for (int i = 0; i < 2; i++) {
        int lr = rt * 2 + i;
        float hv[4];
        *(float4*)hv = *(const float4*)&Hs[lr][ct * 4];
        float outv[4];
#pragma unroll
        for (int j = 0; j < 4; j++) {
            float xr = acc[i][0][j] + bir[j];
            float xz = acc[i][1][j] + biz[j];
            float xn = acc[i][2][j] + bin_[j];
            float hr = acc[i][3][j] + bhr[j];
            float hz = acc[i][4][j] + bhz[j];
            float hn = acc[i][5][j] + bhn[j];
            float r = 1.f / (1.f + expf(-(xr + hr)));
            float z = 1.f / (1.f + expf(-(xz + hz)));
            float n = tanhf(xn + r * hn);
            outv[j] = (1.f - z) * n + z * hv[j];
        }
        *(float4*)&h[(size_t)(row0 + lr) * CC + ct * 4] = *(float4*)outv;
    }
}

// ---------------- fused MLP + log_softmax ----------------
__global__ __launch_bounds__(256) void k_mlp(const float* __restrict__ h,
                                             const float* __restrict__ w0, const float* __restrict__ b0,
                                             const float* __restrict__ w1, const float* __restrict__ b1,
                                             const float* __restrict__ w2, const float* __restrict__ b2,
                                             const float* __restrict__ w3, const float* __restrict__ b3,
                                             float* __restrict__ out) {
    __shared__ float w0s[32 * 128];
    __shared__ float w1s[32 * 32];
    __shared__ float w2s[32 * 32];
    __shared__ float w3s[7 * 32];
    __shared__ float bs[104];            // b0[0:32] b1[32:64] b2[64:96] b3[96:103]
    __shared__ float hs[256][33];        // +1 pad: conflict-free per-row reads
    int t = threadIdx.x;
    for (int i = t; i < 4096; i += 256) w0s[i] = w0[i];
    for (int i = t; i < 1024; i += 256) { w1s[i] = w1[i]; w2s[i] = w2[i]; }
    for (int i = t; i < 224; i += 256) w3s[i] = w3[i];
    if (t < 32) { bs[t] = b0[t]; bs[32 + t] = b1[t]; bs[64 + t] = b2[t]; }
    if (t < 7) bs[96 + t] = b3[t];

    int row = blockIdx.x * 256 + t;
    float acc0[32];
#pragma unroll
    for (int j = 0; j < 32; j++) acc0[j] = 0.f;

    for (int k0 = 0; k0 < 128; k0 += 32) {
        __syncthreads();
#pragma unroll
        for (int it = 0; it < 8; it++) {
            int idx = it * 256 + t;
            int r = idx >> 3, cq = idx & 7;
            int grow = blockIdx.x * 256 + r;
            float4 v = make_float4(0.f, 0.f, 0.f, 0.f);
            if (grow < NN) v = ((const float4*)h)[(size_t)grow * 32 + (k0 >> 2) + cq];
            hs[r][cq * 4 + 0] = v.x;
            hs[r][cq * 4 + 1] = v.y;
            hs[r][cq * 4 + 2] = v.z;
            hs[r][cq * 4 + 3] = v.w;
        }
        __syncthreads();
        for (int kk = 0; kk < 32; kk++) {
            float xk = hs[t][kk];
#pragma unroll
            for (int j = 0; j < 32; j++) acc0[j] += xk * w0s[j * 128 + k0 + kk];
        }
    }
    float v0[32];
#pragma unroll
    for (int j = 0; j < 32; j++) v0[j] = tanhf(acc0[j] + bs[j]);
    float v1[32];
#pragma unroll
    for (int j = 0; j < 32; j++) {
        float s = bs[32 + j];
#pragma unroll
        for (int k = 0; k < 32; k++) s += w1s[j * 32 + k] * v0[k];
        v1[j] = tanhf(s);
    }
    float v2[32];
#pragma unroll
    for (int j = 0; j < 32; j++) {
        float s = bs[64 + j];
#pragma unroll
        for (int k = 0; k < 32; k++) s += w2s[j * 32 + k] * v1[k];
        v2[j] = tanhf(s);
    }
    float y3[7];
#pragma unroll
    for (int j = 0; j < 7; j++) {
        float s = bs[96 + j];
#pragma unroll
        for (int k = 0; k < 32; k++) s += w3s[j * 32 + k] * v2[k];
        y3[j] = s;
    }
    float mx = y3[0];
#pragma unroll
    for (int j = 1; j < 7; j++) mx = fmaxf(mx, y3[j]);
    float se = 0.f;
#pragma unroll
    for (int j = 0; j < 7; j++) se += expf(y3[j] - mx);
    float lse = mx + logf(se);
    if (row < NN) {
#pragma unroll
        for (int j = 0; j < 7; j++) out[(size_t)row * 7 + j] = y3[j] - lse;
    }
}

extern "C" void kernel_launch(void* const* d_in, const int* in_sizes, int n_in,
                              void* d_out, int out_size, void* d_ws, size_t ws_size,
                              hipStream_t stream) {
    const float* x   = (const float*)d_in[0];
    const int*   ei  = (const int*)d_in[1];     // [2, E]
    const float* ew  = (const float*)d_in[2];
    const float* cw  = (const float*)d_in[3];   // [L,128,128]
    const float* wih = (const float*)d_in[4];   // [384,128]
    const float* whh = (const float*)d_in[5];
    const float* bih = (const float*)d_in[6];
    const float* bhh = (const float*)d_in[7];
    const float* w0 = (const float*)d_in[8];
    const float* b0 = (const float*)d_in[9];
    const float* w1 = (const float*)d_in[10];
    const float* b1 = (const float*)d_in[11];
    const float* w2 = (const float*)d_in[12];
    const float* b2 = (const float*)d_in[13];
    const float* w3 = (const float*)d_in[14];
    const float* b3 = (const float*)d_in[15];
    float* out = (float*)d_out;

    float* h     = (float*)d_ws;                 // N*C floats
    float* m     = h + (size_t)NN * CC;          // N*C
    float* agg   = m + (size_t)NN * CC;          // N*C
    float* wih_t = agg + (size_t)NN * CC;        // 128*384
    float* whh_t = wih_t + 3 * CC * CC;          // 128*384
    float* e_w   = whh_t + 3 * CC * CC;          // E floats (CSR-sorted weights)
    int*   e_src = (int*)(e_w + NE);             // E ints (CSR-sorted sources)
    int*   off   = e_src + NE;                   // NN+1
    int*   deg   = off + (NN + 1);               // NN
    int*   cursor= deg + NN;                     // NN

    const int* src = ei;
    const int* dst = ei + NE;

    hipMemcpyAsync(h, x, (size_t)NN * CC * sizeof(float), hipMemcpyDeviceToDevice, stream);
    k_transpose_w<<<192, 256, 0, stream>>>(wih, wih_t);
    k_transpose_w<<<192, 256, 0, stream>>>(whh, whh_t);

    // CSR build (once per call; reused by all 3 layers)
    hipMemsetAsync(deg, 0, NN * sizeof(int), stream);
    k_count<<<(NE + 255) / 256, 256, 0, stream>>>(dst, deg);
    k_scan<<<1, 1024, 0, stream>>>(deg, off);
    hipMemcpyAsync(cursor, off, NN * sizeof(int), hipMemcpyDeviceToDevice, stream);
    k_fill<<<(NE + 255) / 256, 256, 0, stream>>>(src, dst, ew, cursor, e_src, e_w);

    for (int l = 0; l < NL; l++) {
        k_conv<<<NN / 16, 256, 0, stream>>>(h, cw + (size_t)l * CC * CC, m);
        k_agg<<<(NN + 3) / 4, 256, 0, stream>>>(off, e_src, e_w, m, agg);
        k_gru<<<NN / 16, 256, 0, stream>>>(agg, h, wih_t, whh_t, bih, bhh);
    }
    k_mlp<<<(NN + 255) / 256, 256, 0, stream>>>(h, w0, b0, w1, b1, w2, b2, w3, b3, out);
}

// Round 3
// 761.860 us; speedup vs baseline: 5.4730x; 1.9065x over previous
//
#include <hip/hip_runtime.h>
#include <hip/hip_bf16.h>
#include <math.h>

#define NN 50000
#define NE 600000
#define CC 128
#define NL 3

typedef __attribute__((ext_vector_type(8))) short bf16x8;
typedef __attribute__((ext_vector_type(4))) float f32x4;
typedef unsigned short ushort_t;
typedef unsigned int uint_t;

__device__ inline ushort_t f2bf(float f) {
    __hip_bfloat16 b = __float2bfloat16(f);
    return *reinterpret_cast<ushort_t*>(&b);
}
__device__ inline float bf2f(ushort_t u) {
    return __uint_as_float(((uint_t)u) << 16);
}

// ---------------- x -> h (fp32) + h_bf (bf16) ----------------
__global__ __launch_bounds__(256) void k_cvt(const float* __restrict__ x,
                                             float* __restrict__ h,
                                             ushort_t* __restrict__ h_bf) {
    size_t i = (size_t)blockIdx.x * 256 + threadIdx.x;   // over 1.6M float4
    float4 v = ((const float4*)x)[i];
    ((float4*)h)[i] = v;
    ushort4 u;
    u.x = f2bf(v.x); u.y = f2bf(v.y); u.z = f2bf(v.z); u.w = f2bf(v.w);
    ((ushort4*)h_bf)[i] = u;
}

// ---------------- weights -> bf16 (wih/whh straight; cw transposed) ----------------
__global__ __launch_bounds__(256) void k_wcvt(const float* __restrict__ wih,
                                              const float* __restrict__ whh,
                                              const float* __restrict__ cw,
                                              ushort_t* __restrict__ wih_bf,
                                              ushort_t* __restrict__ whh_bf,
                                              ushort_t* __restrict__ cwt_bf) {
    int i = blockIdx.x * 256 + threadIdx.x;    // 49152
    wih_bf[i] = f2bf(wih[i]);
    whh_bf[i] = f2bf(whh[i]);
    int l = i >> 14, rem = i & 16383;
    int c = rem >> 7, k = rem & 127;
    cwt_bf[i] = f2bf(cw[l * 16384 + k * 128 + c]);   // cwt[l][c][k] = cw[l][k][c]
}

// ---------------- CSR build: histogram, scan, fill ----------------
__global__ __launch_bounds__(256) void k_count(const int* __restrict__ dst,
                                               int* __restrict__ deg) {
    int e = blockIdx.x * 256 + threadIdx.x;
    if (e < NE) atomicAdd(&deg[dst[e]], 1);
}

__global__ __launch_bounds__(1024) void k_scan(const int* __restrict__ deg,
                                               int* __restrict__ off) {
    __shared__ int part[1024];
    int t = threadIdx.x;
    const int CH = (NN + 1023) / 1024;   // 49
    int base = t * CH;
    int s = 0;
    for (int i = 0; i < CH; i++) {
        int idx = base + i;
        if (idx < NN) s += deg[idx];
    }
    part[t] = s;
    __syncthreads();
    for (int ofs = 1; ofs < 1024; ofs <<= 1) {
        int v = (t >= ofs) ? part[t - ofs] : 0;
        __syncthreads();
        part[t] += v;
        __syncthreads();
    }
    int run = (t == 0) ? 0 : part[t - 1];
    for (int i = 0; i < CH; i++) {
        int idx = base + i;
        if (idx < NN) { off[idx] = run; run += deg[idx]; }
    }
    if (t == 1023) off[NN] = part[1023];
}

__global__ __launch_bounds__(256) void k_fill(const int* __restrict__ src,
                                              const int* __restrict__ dst,
                                              const float* __restrict__ ew,
                                              int* __restrict__ cursor,
                                              int* __restrict__ e_src,
                                              float* __restrict__ e_w) {
    int e = blockIdx.x * 256 + threadIdx.x;
    if (e >= NE) return;
    int d = dst[e];
    int p = atomicAdd(&cursor[d], 1);
    e_src[p] = src[e];
    e_w[p] = ew[e];
}

// ---------------- m_bf = bf16( h_bf @ W )  via MFMA ----------------
__global__ __launch_bounds__(256) void k_conv(const ushort_t* __restrict__ h_bf,
                                              const ushort_t* __restrict__ cwt_bf,  // [c][k]
                                              ushort_t* __restrict__ m_bf) {
    int wid = (blockIdx.x * 256 + threadIdx.x) >> 6;   // row-group id
    if (wid >= NN / 16) return;
    int l = threadIdx.x & 63;
    int lr = l & 15, lg = l >> 4;
    int n0 = wid * 16;

    bf16x8 a[4];
    {
        const short* ap = (const short*)h_bf + (size_t)(n0 + lr) * CC + lg * 8;
#pragma unroll
        for (int s = 0; s < 4; s++) a[s] = *(const bf16x8*)(ap + s * 32);
    }
    const short* wp = (const short*)cwt_bf + lr * CC + lg * 8;   // + cb*CC + s*32

#pragma unroll
    for (int c0 = 0; c0 < 8; c0++) {
        f32x4 acc = {0.f, 0.f, 0.f, 0.f};
        const short* wc = wp + c0 * 16 * CC;
#pragma unroll
        for (int s = 0; s < 4; s++) {
            bf16x8 b = *(const bf16x8*)(wc + s * 32);
            acc = __builtin_amdgcn_mfma_f32_16x16x32_bf16(a[s], b, acc, 0, 0, 0);
        }
        int c = c0 * 16 + lr;
#pragma unroll
        for (int j = 0; j < 4; j++)
            m_bf[(size_t)(n0 + lg * 4 + j) * CC + c] = f2bf(acc[j]);
    }
}

// ---------------- agg_bf[n] = bf16( sum w_e * m_bf[src_e] )  (wave per node) ----------------
__global__ __launch_bounds__(256) void k_agg(const int* __restrict__ off,
                                             const int* __restrict__ e_src,
                                             const float* __restrict__ e_w,
                                             const ushort_t* __restrict__ m_bf,
                                             ushort_t* __restrict__ agg_bf) {
    int node = blockIdx.x * 4 + (threadIdx.x >> 6);
    int lane = threadIdx.x & 63;
    if (node >= NN) return;
    int b = off[node], e = off[node + 1];
    const uint_t* m2 = (const uint_t*)m_bf;
    float ax = 0.f, ay = 0.f;
    for (int i = b; i < e; i++) {
        int s = e_src[i];
        float w = e_w[i];
        uint_t v = m2[(size_t)s * 64 + lane];
        ax += w * bf2f((ushort_t)(v & 0xffffu));
        ay += w * bf2f((ushort_t)(v >> 16));
    }
    uint_t packed = (uint_t)f2bf(ax) | ((uint_t)f2bf(ay) << 16);
    ((uint_t*)agg_bf)[(size_t)node * 64 + lane] = packed;
}

// ---------------- fused GRU cell via MFMA: h = GRU(agg, h) ----------------
__global__ __launch_bounds__(256) void k_gru(const ushort_t* __restrict__ agg_bf,
                                             float* __restrict__ h,
                                             ushort_t* __restrict__ h_bf,
                                             const ushort_t* __restrict__ wih_bf,  // [384][128]
                                             const ushort_t* __restrict__ whh_bf,
                                             const float* __restrict__ b_ih,
                                             const float* __restrict__ b_hh) {
    int wid = (blockIdx.x * 256 + threadIdx.x) >> 6;
    if (wid >= NN / 16) return;
    int l = threadIdx.x & 63;
    int lr = l & 15, lg = l >> 4;
    int n0 = wid * 16;

    bf16x8 a[4], hf[4];
    {
        const short* ap = (const short*)agg_bf + (size_t)(n0 + lr) * CC + lg * 8;
        const short* hp = (const short*)h_bf + (size_t)(n0 + lr) * CC + lg * 8;
#pragma unroll
        for (int s = 0; s < 4; s++) {
            a[s] = *(const bf16x8*)(ap + s * 32);
            hf[s] = *(const bf16x8*)(hp + s * 32);
        }
    }
    const short* wx = (const short*)wih_bf + lr * CC + lg * 8;
    const short* wh = (const short*)whh_bf + lr * CC + lg * 8;

#pragma unroll
    for (int c0 = 0; c0 < 8; c0++) {
        f32x4 acc0 = {0.f, 0.f, 0.f, 0.f};   // xr
        f32x4 acc1 = {0.f, 0.f, 0.f, 0.f};   // xz
        f32x4 acc2 = {0.f, 0.f, 0.f, 0.f};   // xn
        f32x4 acc3 = {0.f, 0.f, 0.f, 0.f};   // hr
        f32x4 acc4 = {0.f, 0.f, 0.f, 0.f};   // hz
        f32x4 acc5 = {0.f, 0.f, 0.f, 0.f};   // hn
        const short* wxc = wx + c0 * 16 * CC;
        const short* whc = wh + c0 * 16 * CC;
#pragma unroll
        for (int s = 0; s < 4; s++) {
            bf16x8 br = *(const bf16x8*)(wxc + s * 32);
            bf16x8 bz = *(const bf16x8*)(wxc + 128 * CC + s * 32);
            bf16x8 bn = *(const bf16x8*)(wxc + 256 * CC + s * 32);
            acc0 = __builtin_amdgcn_mfma_f32_16x16x32_bf16(a[s], br, acc0, 0, 0, 0);
            acc1 = __builtin_amdgcn_mfma_f32_16x16x32_bf16(a[s], bz, acc1, 0, 0, 0);
            acc2 = __builtin_amdgcn_mfma_f32_16x16x32_bf16(a[s], bn, acc2, 0, 0, 0);
            bf16x8 cr = *(const bf16x8*)(whc + s * 32);
            bf16x8 cz = *(const bf16x8*)(whc + 128 * CC + s * 32);
            bf16x8 cn = *(const bf16x8*)(whc + 256 * CC + s * 32);
            acc3 = __builtin_amdgcn_mfma_f32_16x16x32_bf16(hf[s], cr, acc3, 0, 0, 0);
            acc4 = __builtin_amdgcn_mfma_f32_16x16x32_bf16(hf[s], cz, acc4, 0, 0, 0);
            acc5 = __builtin_amdgcn_mfma_f32_16x16x32_bf16(hf[s], cn, acc5, 0, 0, 0);
        }
        int c = c0 * 16 + lr;
        float bir = b_ih[c], biz = b_ih[128 + c], bin = b_ih[256 + c];
        float bhr = b_hh[c], bhz = b_hh[128 + c], bhn = b_hh[256 + c];
#pragma unroll
        for (int j = 0; j < 4; j++) {
            size_t row = (size_t)(n0 + lg * 4 + j);
            float hv = h[row * CC + c];
            float rg = 1.f / (1.f + expf(-(acc0[j] + bir + acc3[j] + bhr)));
            float zg = 1.f / (1.f + expf(-(acc1[j] + biz + acc4[j] + bhz)));
            float ng = tanhf(acc2[j] + bin + rg * (acc5[j] + bhn));
            float hn2 = (1.f - zg) * ng + zg * hv;
            h[row * CC + c] = hn2;
            h_bf[row * CC + c] = f2bf(hn2);
        }
    }
}

// ---------------- fused MLP + log_softmax ----------------
__global__ __launch_bounds__(256) void k_mlp(const float* __restrict__ h,
                                             const float* __restrict__ w0, const float* __restrict__ b0,
                                             const float* __restrict__ w1, const float* __restrict__ b1,
                                             const float* __restrict__ w2, const float* __restrict__ b2,
                                             const float* __restrict__ w3, const float* __restrict__ b3,
                                             float* __restrict__ out) {
    __shared__ float w0s[32 * 128];
    __shared__ float w1s[32 * 32];
    __shared__ float w2s[32 * 32];
    __shared__ float w3s[7 * 32];
    __shared__ float bs[104];
    __shared__ float hs[256][33];
    int t = threadIdx.x;
    for (int i = t; i < 4096; i += 256) w0s[i] = w0[i];
    for (int i = t; i < 1024; i += 256) { w1s[i] = w1[i]; w2s[i] = w2[i]; }
    for (int i = t; i < 224; i += 256) w3s[i] = w3[i];
    if (t < 32) { bs[t] = b0[t]; bs[32 + t] = b1[t]; bs[64 + t] = b2[t]; }
    if (t < 7) bs[96 + t] = b3[t];

    int row = blockIdx.x * 256 + t;
    float acc0[32];
#pragma unroll
    for (int j = 0; j < 32; j++) acc0[j] = 0.f;

    for (int k0 = 0; k0 < 128; k0 += 32) {
        __syncthreads();
#pragma unroll
        for (int it = 0; it < 8; it++) {
            int idx = it * 256 + t;
            int r = idx >> 3, cq = idx & 7;
            int grow = blockIdx.x * 256 + r;
            float4 v = make_float4(0.f, 0.f, 0.f, 0.f);
            if (grow < NN) v = ((const float4*)h)[(size_t)grow * 32 + (k0 >> 2) + cq];
            hs[r][cq * 4 + 0] = v.x;
            hs[r][cq * 4 + 1] = v.y;
            hs[r][cq * 4 + 2] = v.z;
            hs[r][cq * 4 + 3] = v.w;
        }
        __syncthreads();
        for (int kk = 0; kk < 32; kk++) {
            float xk = hs[t][kk];
#pragma unroll
            for (int j = 0; j < 32; j++) acc0[j] += xk * w0s[j * 128 + k0 + kk];
        }
    }
    float v0[32];
#pragma unroll
    for (int j = 0; j < 32; j++) v0[j] = tanhf(acc0[j] + bs[j]);
    float v1[32];
#pragma unroll
    for (int j = 0; j < 32; j++) {
        float s = bs[32 + j];
#pragma unroll
        for (int k = 0; k < 32; k++) s += w1s[j * 32 + k] * v0[k];
        v1[j] = tanhf(s);
    }
    float v2[32];
#pragma unroll
    for (int j = 0; j < 32; j++) {
        float s = bs[64 + j];
#pragma unroll
        for (int k = 0; k < 32; k++) s += w2s[j * 32 + k] * v1[k];
        v2[j] = tanhf(s);
    }
    float y3[7];
#pragma unroll
    for (int j = 0; j < 7; j++) {
        float s = bs[96 + j];
#pragma unroll
        for (int k = 0; k < 32; k++) s += w3s[j * 32 + k] * v2[k];
        y3[j] = s;
    }
    float mx = y3[0];
#pragma unroll
    for (int j = 1; j < 7; j++) mx = fmaxf(mx, y3[j]);
    float se = 0.f;
#pragma unroll
    for (int j = 0; j < 7; j++) se += expf(y3[j] - mx);
    float lse = mx + logf(se);
    if (row < NN) {
#pragma unroll
        for (int j = 0; j < 7; j++) out[(size_t)row * 7 + j] = y3[j] - lse;
    }
}

extern "C" void kernel_launch(void* const* d_in, const int* in_sizes, int n_in,
                              void* d_out, int out_size, void* d_ws, size_t ws_size,
                              hipStream_t stream) {
    const float* x   = (const float*)d_in[0];
    const int*   ei  = (const int*)d_in[1];     // [2, E]
    const float* ew  = (const float*)d_in[2];
    const float* cw  = (const float*)d_in[3];   // [L,128,128]
    const float* wih = (const float*)d_in[4];   // [384,128]
    const float* whh = (const float*)d_in[5];
    const float* bih = (const float*)d_in[6];
    const float* bhh = (const float*)d_in[7];
    const float* w0 = (const float*)d_in[8];
    const float* b0 = (const float*)d_in[9];
    const float* w1 = (const float*)d_in[10];
    const float* b1 = (const float*)d_in[11];
    const float* w2 = (const float*)d_in[12];
    const float* b2 = (const float*)d_in[13];
    const float* w3 = (const float*)d_in[14];
    const float* b3 = (const float*)d_in[15];
    float* out = (float*)d_out;

    float*    h      = (float*)d_ws;                   // 6.4e6 fp32
    ushort_t* h_bf   = (ushort_t*)(h + (size_t)NN * CC);
    ushort_t* m_bf   = h_bf + (size_t)NN * CC;
    ushort_t* agg_bf = m_bf + (size_t)NN * CC;
    ushort_t* wih_bf = agg_bf + (size_t)NN * CC;       // 49152
    ushort_t* whh_bf = wih_bf + 3 * CC * CC;
    ushort_t* cwt_bf = whh_bf + 3 * CC * CC;
    float*    e_w    = (float*)(cwt_bf + 3 * CC * CC);
    int*      e_src  = (int*)(e_w + NE);
    int*      off    = e_src + NE;
    int*      deg    = off + (NN + 1);
    int*      cursor = deg + NN;

    const int* src = ei;
    const int* dst = ei + NE;

    k_cvt<<<(NN * CC) / 1024, 256, 0, stream>>>(x, h, h_bf);
    k_wcvt<<<192, 256, 0, stream>>>(wih, whh, cw, wih_bf, whh_bf, cwt_bf);

    // CSR build (once per call)
    hipMemsetAsync(deg, 0, NN * sizeof(int), stream);
    k_count<<<(NE + 255) / 256, 256, 0, stream>>>(dst, deg);
    k_scan<<<1, 1024, 0, stream>>>(deg, off);
    hipMemcpyAsync(cursor, off, NN * sizeof(int), hipMemcpyDeviceToDevice, stream);
    k_fill<<<(NE + 255) / 256, 256, 0, stream>>>(src, dst, ew, cursor, e_src, e_w);

    const int ngrp = NN / 16;                  // 3125 row-groups
    const int nblk = (ngrp + 3) / 4;           // 4 waves per block
    for (int l = 0; l < NL; l++) {
        k_conv<<<nblk, 256, 0, stream>>>(h_bf, cwt_bf + (size_t)l * CC * CC, m_bf);
        k_agg<<<(NN + 3) / 4, 256, 0, stream>>>(off, e_src, e_w, m_bf, agg_bf);
        k_gru<<<nblk, 256, 0, stream>>>(agg_bf, h, h_bf, wih_bf, whh_bf, bih, bhh);
    }
    k_mlp<<<(NN + 255) / 256, 256, 0, stream>>>(h, w0, b0, w1, b1, w2, b2, w3, b3, out);
}

// Round 4
// 488.226 us; speedup vs baseline: 8.5404x; 1.5605x over previous
//
#include <hip/hip_runtime.h>
#include <hip/hip_bf16.h>
#include <math.h>

#define NN 50000
#define NE 600000
#define CC 128
#define NL 3
#define NRG (NN / 16)      // 3125 row-groups
#define G_RG 8             // row-groups per gru wave

typedef __attribute__((ext_vector_type(8))) short bf16x8;
typedef __attribute__((ext_vector_type(4))) float f32x4;
typedef unsigned short ushort_t;
typedef unsigned int uint_t;

__device__ inline ushort_t f2bf(float f) {
    __hip_bfloat16 b = __float2bfloat16(f);
    return *reinterpret_cast<ushort_t*>(&b);
}
__device__ inline float bf2f(ushort_t u) {
    return __uint_as_float(((uint_t)u) << 16);
}

// ---------------- x -> hbf0 (bf16) ----------------
__global__ __launch_bounds__(256) void k_cvt(const float* __restrict__ x,
                                             ushort_t* __restrict__ h_bf) {
    size_t i = (size_t)blockIdx.x * 256 + threadIdx.x;   // over 1.6M float4
    float4 v = ((const float4*)x)[i];
    ushort4 u;
    u.x = f2bf(v.x); u.y = f2bf(v.y); u.z = f2bf(v.z); u.w = f2bf(v.w);
    ((ushort4*)h_bf)[i] = u;
}

// ---------------- GRU weights -> packed bf16 fragments ----------------
// frag F = (c0*3+g)*4+s; lane l=(lr,lg); elem e:  pk[(F*64+l)*8+e] = W[g*128+c0*16+lr][s*32+lg*8+e]
__global__ __launch_bounds__(256) void k_wpack(const float* __restrict__ W,
                                               ushort_t* __restrict__ pk) {
    int tid = blockIdx.x * 256 + threadIdx.x;    // 49152
    int e = tid & 7;
    int l = (tid >> 3) & 63;
    int s = (tid >> 9) & 3;
    int rest = tid >> 11;                        // c0*3+g, 0..23
    int g = rest % 3, c0 = rest / 3;
    int row = g * 128 + c0 * 16 + (l & 15);
    int col = s * 32 + (l >> 4) * 8 + e;
    pk[tid] = f2bf(W[row * 128 + col]);
}

// ---------------- conv weights -> packed bf16 fragments (3 layers) ----------------
// frag F = layer*32 + c0*4+s; pk[(F*64+l)*8+e] = cw[layer][k=s*32+lg*8+e][c=c0*16+lr]
__global__ __launch_bounds__(256) void k_cpack(const float* __restrict__ cw,
                                               ushort_t* __restrict__ pk) {
    int tid = blockIdx.x * 256 + threadIdx.x;    // 49152
    int e = tid & 7;
    int l = (tid >> 3) & 63;
    int s = (tid >> 9) & 3;
    int rest = tid >> 11;                        // layer*8 + c0
    int c0 = rest & 7, layer = rest >> 3;
    int c = c0 * 16 + (l & 15);
    int k = s * 32 + (l >> 4) * 8 + e;
    pk[tid] = f2bf(cw[layer * 16384 + k * 128 + c]);
}

// ---------------- CSR build: histogram, scan, fill ----------------
__global__ __launch_bounds__(256) void k_count(const int* __restrict__ dst,
                                               int* __restrict__ deg) {
    int e = blockIdx.x * 256 + threadIdx.x;
    if (e < NE) atomicAdd(&deg[dst[e]], 1);
}

__global__ __launch_bounds__(1024) void k_scan(const int* __restrict__ deg,
                                               int* __restrict__ off) {
    __shared__ int part[1024];
    int t = threadIdx.x;
    const int CH = (NN + 1023) / 1024;   // 49
    int base = t * CH;
    int s = 0;
    for (int i = 0; i < CH; i++) {
        int idx = base + i;
        if (idx < NN) s += deg[idx];
    }
    part[t] = s;
    __syncthreads();
    for (int ofs = 1; ofs < 1024; ofs <<= 1) {
        int v = (t >= ofs) ? part[t - ofs] : 0;
        __syncthreads();
        part[t] += v;
        __syncthreads();
    }
    int run = (t == 0) ? 0 : part[t - 1];
    for (int i = 0; i < CH; i++) {
        int idx = base + i;
        if (idx < NN) { off[idx] = run; run += deg[idx]; }
    }
    if (t == 1023) off[NN] = part[1023];
}

__global__ __launch_bounds__(256) void k_fill(const int* __restrict__ src,
                                              const int* __restrict__ dst,
                                              const float* __restrict__ ew,
                                              int* __restrict__ cursor,
                                              int* __restrict__ e_src,
                                              float* __restrict__ e_w) {
    int e = blockIdx.x * 256 + threadIdx.x;
    if (e >= NE) return;
    int d = dst[e];
    int p = atomicAdd(&cursor[d], 1);
    e_src[p] = src[e];
    e_w[p] = ew[e];
}

// ---------------- m_bf = bf16( h_bf @ W )  via MFMA, packed weights ----------------
__global__ __launch_bounds__(256) void k_conv(const ushort_t* __restrict__ h_bf,
                                              const ushort_t* __restrict__ cw_pk,  // layer offset applied
                                              ushort_t* __restrict__ m_bf) {
    int wid = (blockIdx.x * 256 + threadIdx.x) >> 6;
    if (wid >= NRG) return;
    int l = threadIdx.x & 63;
    int lr = l & 15, lg = l >> 4;
    int n0 = wid * 16;

    bf16x8 a[4];
    {
        const short* ap = (const short*)h_bf + (size_t)(n0 + lr) * CC + lg * 8;
#pragma unroll
        for (int s = 0; s < 4; s++) a[s] = *(const bf16x8*)(ap + s * 32);
    }
    const bf16x8* pw = (const bf16x8*)cw_pk;
#pragma unroll
    for (int c0 = 0; c0 < 8; c0++) {
        f32x4 acc = {0.f, 0.f, 0.f, 0.f};
#pragma unroll
        for (int s = 0; s < 4; s++)
            acc = __builtin_amdgcn_mfma_f32_16x16x32_bf16(a[s], pw[(c0 * 4 + s) * 64 + l], acc, 0, 0, 0);
        int c = c0 * 16 + lr;
#pragma unroll
        for (int j = 0; j < 4; j++)
            m_bf[(size_t)(n0 + lg * 4 + j) * CC + c] = f2bf(acc[j]);
    }
}

// ---------------- agg_bf[n] = bf16( sum w_e * m_bf[src_e] ), 4x unrolled gather ----------------
__global__ __launch_bounds__(256) void k_agg(const int* __restrict__ off,
                                             const int* __restrict__ e_src,
                                             const float* __restrict__ e_w,
                                             const ushort_t* __restrict__ m_bf,
                                             ushort_t* __restrict__ agg_bf) {
    int node = blockIdx.x * 4 + (threadIdx.x >> 6);
    int lane = threadIdx.x & 63;
    if (node >= NN) return;
    int b = off[node], e = off[node + 1];
    const uint_t* m2 = (const uint_t*)m_bf;
    float ax = 0.f, ay = 0.f;
    int i = b;
    for (; i + 4 <= e; i += 4) {
        int s0 = e_src[i], s1 = e_src[i + 1], s2 = e_src[i + 2], s3 = e_src[i + 3];
        float w0 = e_w[i], w1 = e_w[i + 1], w2 = e_w[i + 2], w3 = e_w[i + 3];
        uint_t v0 = m2[(size_t)s0 * 64 + lane];
        uint_t v1 = m2[(size_t)s1 * 64 + lane];
        uint_t v2 = m2[(size_t)s2 * 64 + lane];
        uint_t v3 = m2[(size_t)s3 * 64 + lane];
        ax += w0 * bf2f((ushort_t)(v0 & 0xffffu)) + w1 * bf2f((ushort_t)(v1 & 0xffffu))
            + w2 * bf2f((ushort_t)(v2 & 0xffffu)) + w3 * bf2f((ushort_t)(v3 & 0xffffu));
        ay += w0 * bf2f((ushort_t)(v0 >> 16)) + w1 * bf2f((ushort_t)(v1 >> 16))
            + w2 * bf2f((ushort_t)(v2 >> 16)) + w3 * bf2f((ushort_t)(v3 >> 16));
    }
    for (; i < e; i++) {
        int s = e_src[i];
        float w = e_w[i];
        uint_t v = m2[(size_t)s * 64 + lane];
        ax += w * bf2f((ushort_t)(v & 0xffffu));
        ay += w * bf2f((ushort_t)(v >> 16));
    }
    uint_t packed = (uint_t)f2bf(ax) | ((uint_t)f2bf(ay) << 16);
    ((uint_t*)agg_bf)[(size_t)node * 64 + lane] = packed;
}

// ---------------- fused GRU cell, weight-resident waves ----------------
// wave = (c0, chunk); holds 24 B-frags resident; streams G_RG row-groups.
__global__ __launch_bounds__(256, 2) void k_gru(const ushort_t* __restrict__ agg_bf,
                                                const ushort_t* __restrict__ hbf_in,
                                                ushort_t* __restrict__ hbf_out,
                                                const float* __restrict__ h_in,
                                                float* __restrict__ h_out,
                                                const ushort_t* __restrict__ wx_pk,
                                                const ushort_t* __restrict__ wh_pk,
                                                const float* __restrict__ b_ih,
                                                const float* __restrict__ b_hh) {
    int wid = (blockIdx.x * 256 + threadIdx.x) >> 6;
    int l = threadIdx.x & 63;
    int c0 = wid & 7;
    int chunk = wid >> 3;
    int lr = l & 15, lg = l >> 4;

    // resident weight fragments: BX[g*4+s], BH[g*4+s]
    bf16x8 BX[12], BH[12];
    {
        const bf16x8* px = (const bf16x8*)wx_pk + (size_t)c0 * 12 * 64 + l;
        const bf16x8* ph = (const bf16x8*)wh_pk + (size_t)c0 * 12 * 64 + l;
#pragma unroll
        for (int f = 0; f < 12; f++) { BX[f] = px[f * 64]; BH[f] = ph[f * 64]; }
    }
    int c = c0 * 16 + lr;
    float bxr = b_ih[c], bxz = b_ih[128 + c], bxn = b_ih[256 + c];
    float bhr = b_hh[c], bhz = b_hh[128 + c], bhn = b_hh[256 + c];

    for (int it = 0; it < G_RG; it++) {
        int rg = chunk * G_RG + it;
        if (rg >= NRG) break;
        int n0 = rg * 16;
        const short* ap = (const short*)agg_bf + (size_t)(n0 + lr) * CC + lg * 8;
        const short* hp = (const short*)hbf_in + (size_t)(n0 + lr) * CC + lg * 8;
        bf16x8 a[4], hf[4];
#pragma unroll
        for (int s = 0; s < 4; s++) {
            a[s] = *(const bf16x8*)(ap + s * 32);
            hf[s] = *(const bf16x8*)(hp + s * 32);
        }
        float hv[4];
#pragma unroll
        for (int j = 0; j < 4; j++) hv[j] = h_in[(size_t)(n0 + lg * 4 + j) * CC + c];

        f32x4 r0 = {0.f,0.f,0.f,0.f}, r1 = {0.f,0.f,0.f,0.f}, r2 = {0.f,0.f,0.f,0.f};
        f32x4 r3 = {0.f,0.f,0.f,0.f}, r4 = {0.f,0.f,0.f,0.f}, r5 = {0.f,0.f,0.f,0.f};
#pragma unroll
        for (int s = 0; s < 4; s++) {
            r0 = __builtin_amdgcn_mfma_f32_16x16x32_bf16(a[s], BX[s], r0, 0, 0, 0);
            r1 = __builtin_amdgcn_mfma_f32_16x16x32_bf16(a[s], BX[4 + s], r1, 0, 0, 0);
            r2 = __builtin_amdgcn_mfma_f32_16x16x32_bf16(a[s], BX[8 + s], r2, 0, 0, 0);
            r3 = __builtin_amdgcn_mfma_f32_16x16x32_bf16(hf[s], BH[s], r3, 0, 0, 0);
            r4 = __builtin_amdgcn_mfma_f32_16x16x32_bf16(hf[s], BH[4 + s], r4, 0, 0, 0);
            r5 = __builtin_amdgcn_mfma_f32_16x16x32_bf16(hf[s], BH[8 + s], r5, 0, 0, 0);
        }
#pragma unroll
        for (int j = 0; j < 4; j++) {
            size_t row = (size_t)(n0 + lg * 4 + j);
            float rg_ = 1.f / (1.f + expf(-(r0[j] + bxr + r3[j] + bhr)));
            float zg = 1.f / (1.f + expf(-(r1[j] + bxz + r4[j] + bhz)));
            float ng = tanhf(r2[j] + bxn + rg_ * (r5[j] + bhn));
            float hn2 = (1.f - zg) * ng + zg * hv[j];
            h_out[row * CC + c] = hn2;
            hbf_out[row * CC + c] = f2bf(hn2);
        }
    }
}

// ---------------- fused MLP + log_softmax ----------------
__global__ __launch_bounds__(256) void k_mlp(const float* __restrict__ h,
                                             const float* __restrict__ w0, const float* __restrict__ b0,
                                             const float* __restrict__ w1, const float* __restrict__ b1,
                                             const float* __restrict__ w2, const float* __restrict__ b2,
                                             const float* __restrict__ w3, const float* __restrict__ b3,
                                             float* __restrict__ out) {
    __shared__ float w0s[32 * 128];
    __shared__ float w1s[32 * 32];
    __shared__ float w2s[32 * 32];
    __shared__ float w3s[7 * 32];
    __shared__ float bs[104];
    __shared__ float hs[256][33];
    int t = threadIdx.x;
    for (int i = t; i < 4096; i += 256) w0s[i] = w0[i];
    for (int i = t; i < 1024; i += 256) { w1s[i] = w1[i]; w2s[i] = w2[i]; }
    for (int i = t; i < 224; i += 256) w3s[i] = w3[i];
    if (t < 32) { bs[t] = b0[t]; bs[32 + t] = b1[t]; bs[64 + t] = b2[t]; }
    if (t < 7) bs[96 + t] = b3[t];

    int row = blockIdx.x * 256 + t;
    float acc0[32];
#pragma unroll
    for (int j = 0; j < 32; j++) acc0[j] = 0.f;

    for (int k0 = 0; k0 < 128; k0 += 32) {
        __syncthreads();
#pragma unroll
        for (int it = 0; it < 8; it++) {
            int idx = it * 256 + t;
            int r = idx >> 3, cq = idx & 7;
            int grow = blockIdx.x * 256 + r;
            float4 v = make_float4(0.f, 0.f, 0.f, 0.f);
            if (grow < NN) v = ((const float4*)h)[(size_t)grow * 32 + (k0 >> 2) + cq];
            hs[r][cq * 4 + 0] = v.x;
            hs[r][cq * 4 + 1] = v.y;
            hs[r][cq * 4 + 2] = v.z;
            hs[r][cq * 4 + 3] = v.w;
        }
        __syncthreads();
        for (int kk = 0; kk < 32; kk++) {
            float xk = hs[t][kk];
#pragma unroll
            for (int j = 0; j < 32; j++) acc0[j] += xk * w0s[j * 128 + k0 + kk];
        }
    }
    float v0[32];
#pragma unroll
    for (int j = 0; j < 32; j++) v0[j] = tanhf(acc0[j] + bs[j]);
    float v1[32];
#pragma unroll
    for (int j = 0; j < 32; j++) {
        float s = bs[32 + j];
#pragma unroll
        for (int k = 0; k < 32; k++) s += w1s[j * 32 + k] * v0[k];
        v1[j] = tanhf(s);
    }
    float v2[32];
#pragma unroll
    for (int j = 0; j < 32; j++) {
        float s = bs[64 + j];
#pragma unroll
        for (int k = 0; k < 32; k++) s += w2s[j * 32 + k] * v1[k];
        v2[j] = tanhf(s);
    }
    float y3[7];
#pragma unroll
    for (int j = 0; j < 7; j++) {
        float s = bs[96 + j];
#pragma unroll
        for (int k = 0; k < 32; k++) s += w3s[j * 32 + k] * v2[k];
        y3[j] = s;
    }
    float mx = y3[0];
#pragma unroll
    for (int j = 1; j < 7; j++) mx = fmaxf(mx, y3[j]);
    float se = 0.f;
#pragma unroll
    for (int j = 0; j < 7; j++) se += expf(y3[j] - mx);
    float lse = mx + logf(se);
    if (row < NN) {
#pragma unroll
        for (int j = 0; j < 7; j++) out[(size_t)row * 7 + j] = y3[j] - lse;
    }
}

extern "C" void kernel_launch(void* const* d_in, const int* in_sizes, int n_in,
                              void* d_out, int out_size, void* d_ws, size_t ws_size,
                              hipStream_t stream) {
    const float* x   = (const float*)d_in[0];
    const int*   ei  = (const int*)d_in[1];     // [2, E]
    const float* ew  = (const float*)d_in[2];
    const float* cw  = (const float*)d_in[3];   // [L,128,128]
    const float* wih = (const float*)d_in[4];   // [384,128]
    const float* whh = (const float*)d_in[5];
    const float* bih = (const float*)d_in[6];
    const float* bhh = (const float*)d_in[7];
    const float* w0 = (const float*)d_in[8];
    const float* b0 = (const float*)d_in[9];
    const float* w1 = (const float*)d_in[10];
    const float* b1 = (const float*)d_in[11];
    const float* w2 = (const float*)d_in[12];
    const float* b2 = (const float*)d_in[13];
    const float* w3 = (const float*)d_in[14];
    const float* b3 = (const float*)d_in[15];
    float* out = (float*)d_out;

    float*    h     = (float*)d_ws;                    // N*C fp32
    ushort_t* hbf0  = (ushort_t*)(h + (size_t)NN * CC);
    ushort_t* hbf1  = hbf0 + (size_t)NN * CC;
    ushort_t* m_bf  = hbf1 + (size_t)NN * CC;
    ushort_t* agg_bf= m_bf + (size_t)NN * CC;
    ushort_t* wx_pk = agg_bf + (size_t)NN * CC;        // 49152
    ushort_t* wh_pk = wx_pk + 3 * CC * CC;
    ushort_t* cw_pk = wh_pk + 3 * CC * CC;
    float*    e_w   = (float*)(cw_pk + 3 * CC * CC);
    int*      e_src = (int*)(e_w + NE);
    int*      off   = e_src + NE;
    int*      deg   = off + (NN + 1);
    int*      cursor= deg + NN;

    const int* src = ei;
    const int* dst = ei + NE;

    k_cvt<<<(NN * CC) / 1024, 256, 0, stream>>>(x, hbf0);
    k_wpack<<<192, 256, 0, stream>>>(wih, wx_pk);
    k_wpack<<<192, 256, 0, stream>>>(whh, wh_pk);
    k_cpack<<<192, 256, 0, stream>>>(cw, cw_pk);

    // CSR build (once per call)
    hipMemsetAsync(deg, 0, NN * sizeof(int), stream);
    k_count<<<(NE + 255) / 256, 256, 0, stream>>>(dst, deg);
    k_scan<<<1, 1024, 0, stream>>>(deg, off);
    hipMemcpyAsync(cursor, off, NN * sizeof(int), hipMemcpyDeviceToDevice, stream);
    k_fill<<<(NE + 255) / 256, 256, 0, stream>>>(src, dst, ew, cursor, e_src, e_w);

    const int conv_blk = (NRG + 3) / 4;                       // 4 waves/block
    const int gru_waves = 8 * ((NRG + G_RG - 1) / G_RG);      // 8 c0 x 391 chunks
    const int gru_blk = (gru_waves + 3) / 4;

    ushort_t* hin = hbf0;
    ushort_t* hout = hbf1;
    for (int l = 0; l < NL; l++) {
        k_conv<<<conv_blk, 256, 0, stream>>>(hin, cw_pk + (size_t)l * CC * CC, m_bf);
        k_agg<<<(NN + 3) / 4, 256, 0, stream>>>(off, e_src, e_w, m_bf, agg_bf);
        k_gru<<<gru_blk, 256, 0, stream>>>(agg_bf, hin, hout,
                                           (l == 0) ? x : h, h, wx_pk, wh_pk, bih, bhh);
        ushort_t* tmp = hin; hin = hout; hout = tmp;
    }
    k_mlp<<<(NN + 255) / 256, 256, 0, stream>>>(h, w0, b0, w1, b1, w2, b2, w3, b3, out);
}

// Round 5
// 396.611 us; speedup vs baseline: 10.5132x; 1.2310x over previous
//
#include <hip/hip_runtime.h>
#include <hip/hip_bf16.h>
#include <math.h>

#define NN 50000
#define NE 600000
#define CC 128
#define NL 3
#define NRG (NN / 16)      // 3125 row-groups
#define G_RG 8             // row-groups per weight-resident wave
#define SCAN_B 196         // ceil(NN/256)

typedef __attribute__((ext_vector_type(8))) short bf16x8;
typedef __attribute__((ext_vector_type(4))) float f32x4;
typedef unsigned short ushort_t;
typedef unsigned int uint_t;

__device__ inline ushort_t f2bf(float f) {
    __hip_bfloat16 b = __float2bfloat16(f);
    return *reinterpret_cast<ushort_t*>(&b);
}
__device__ inline float bf2f(ushort_t u) {
    return __uint_as_float(((uint_t)u) << 16);
}

// ---------------- x -> hbf0 (bf16) ----------------
__global__ __launch_bounds__(256) void k_cvt(const float* __restrict__ x,
                                             ushort_t* __restrict__ h_bf) {
    size_t i = (size_t)blockIdx.x * 256 + threadIdx.x;
    float4 v = ((const float4*)x)[i];
    ushort4 u;
    u.x = f2bf(v.x); u.y = f2bf(v.y); u.z = f2bf(v.z); u.w = f2bf(v.w);
    ((ushort4*)h_bf)[i] = u;
}

// ---------------- GRU weights -> packed bf16 fragments ----------------
__global__ __launch_bounds__(256) void k_wpack(const float* __restrict__ W,
                                               ushort_t* __restrict__ pk) {
    int tid = blockIdx.x * 256 + threadIdx.x;    // 49152
    int e = tid & 7;
    int l = (tid >> 3) & 63;
    int s = (tid >> 9) & 3;
    int rest = tid >> 11;                        // c0*3+g
    int g = rest % 3, c0 = rest / 3;
    int row = g * 128 + c0 * 16 + (l & 15);
    int col = s * 32 + (l >> 4) * 8 + e;
    pk[tid] = f2bf(W[row * 128 + col]);
}

// ---------------- conv weights -> packed bf16 fragments (3 layers) ----------------
__global__ __launch_bounds__(256) void k_cpack(const float* __restrict__ cw,
                                               ushort_t* __restrict__ pk) {
    int tid = blockIdx.x * 256 + threadIdx.x;    // 49152
    int e = tid & 7;
    int l = (tid >> 3) & 63;
    int s = (tid >> 9) & 3;
    int rest = tid >> 11;                        // layer*8 + c0
    int c0 = rest & 7, layer = rest >> 3;
    int c = c0 * 16 + (l & 15);
    int k = s * 32 + (l >> 4) * 8 + e;
    pk[tid] = f2bf(cw[layer * 16384 + k * 128 + c]);
}

// ---------------- CSR build ----------------
__global__ __launch_bounds__(256) void k_count(const int* __restrict__ dst,
                                               int* __restrict__ deg) {
    int e = blockIdx.x * 256 + threadIdx.x;
    if (e < NE) atomicAdd(&deg[dst[e]], 1);
}

__global__ __launch_bounds__(256) void k_scan1(const int* __restrict__ deg,
                                               int* __restrict__ off,
                                               int* __restrict__ bsum) {
    __shared__ int sm[256];
    int t = threadIdx.x, i = blockIdx.x * 256 + t;
    int v = (i < NN) ? deg[i] : 0;
    sm[t] = v;
    __syncthreads();
#pragma unroll
    for (int ofs = 1; ofs < 256; ofs <<= 1) {
        int u = (t >= ofs) ? sm[t - ofs] : 0;
        __syncthreads();
        sm[t] += u;
        __syncthreads();
    }
    if (i < NN) off[i] = sm[t] - v;          // exclusive within block
    if (t == 255) bsum[blockIdx.x] = sm[255];
}

__global__ __launch_bounds__(256) void k_scan2(const int* __restrict__ bsum,
                                               int* __restrict__ bofs,
                                               int* __restrict__ off) {
    __shared__ int sm[256];
    int t = threadIdx.x;
    int v = (t < SCAN_B) ? bsum[t] : 0;
    sm[t] = v;
    __syncthreads();
#pragma unroll
    for (int ofs = 1; ofs < 256; ofs <<= 1) {
        int u = (t >= ofs) ? sm[t - ofs] : 0;
        __syncthreads();
        sm[t] += u;
        __syncthreads();
    }
    if (t < SCAN_B) bofs[t] = sm[t] - v;
    if (t == 255) off[NN] = sm[255];
}

__global__ __launch_bounds__(256) void k_scan3(int* __restrict__ off,
                                               const int* __restrict__ bofs,
                                               int* __restrict__ cursor) {
    int t = threadIdx.x, i = blockIdx.x * 256 + t;
    if (i < NN) {
        int o = off[i] + bofs[blockIdx.x];
        off[i] = o;
        cursor[i] = o;
    }
}

__global__ __launch_bounds__(256) void k_fill(const int* __restrict__ src,
                                              const int* __restrict__ dst,
                                              const float* __restrict__ ew,
                                              int* __restrict__ cursor,
                                              int* __restrict__ e_src,
                                              float* __restrict__ e_w) {
    int e = blockIdx.x * 256 + threadIdx.x;
    if (e >= NE) return;
    int d = dst[e];
    int p = atomicAdd(&cursor[d], 1);
    e_src[p] = src[e];
    e_w[p] = ew[e];
}

// ---------------- m_bf = bf16( h_bf @ W ), weight-resident waves ----------------
// wave = (c0g, chunk); holds 8 B-frags (c0g, c0g+4) resident; streams G_RG row-groups.
__global__ __launch_bounds__(256, 2) void k_conv(const ushort_t* __restrict__ h_bf,
                                                 const ushort_t* __restrict__ cw_pk,
                                                 ushort_t* __restrict__ m_bf) {
    int wid = (blockIdx.x * 256 + threadIdx.x) >> 6;
    int l = threadIdx.x & 63;
    int lr = l & 15, lg = l >> 4;
    int c0g = wid & 3;
    int chunk = wid >> 2;

    bf16x8 B[2][4];
    {
        const bf16x8* pw = (const bf16x8*)cw_pk;
#pragma unroll
        for (int p = 0; p < 2; p++)
#pragma unroll
            for (int s = 0; s < 4; s++)
                B[p][s] = pw[(size_t)(((c0g + 4 * p) * 4 + s) * 64) + l];
    }
    int c_lo = c0g * 16 + lr;

    for (int it = 0; it < G_RG; it++) {
        int rg = chunk * G_RG + it;
        if (rg >= NRG) break;
        int n0 = rg * 16;
        const short* ap = (const short*)h_bf + (size_t)(n0 + lr) * CC + lg * 8;
        bf16x8 a[4];
#pragma unroll
        for (int s = 0; s < 4; s++) a[s] = *(const bf16x8*)(ap + s * 32);
        f32x4 acc0 = {0.f,0.f,0.f,0.f}, acc1 = {0.f,0.f,0.f,0.f};
#pragma unroll
        for (int s = 0; s < 4; s++) {
            acc0 = __builtin_amdgcn_mfma_f32_16x16x32_bf16(a[s], B[0][s], acc0, 0, 0, 0);
            acc1 = __builtin_amdgcn_mfma_f32_16x16x32_bf16(a[s], B[1][s], acc1, 0, 0, 0);
        }
#pragma unroll
        for (int j = 0; j < 4; j++) {
            size_t row = (size_t)(n0 + lg * 4 + j) * CC;
            m_bf[row + c_lo] = f2bf(acc0[j]);
            m_bf[row + c_lo + 64] = f2bf(acc1[j]);
        }
    }
}

// ---------------- agg_bf[n] = bf16( sum w_e * m_bf[src_e] ), 8x unrolled gather ----------------
__global__ __launch_bounds__(256) void k_agg(const int* __restrict__ off,
                                             const int* __restrict__ e_src,
                                             const float* __restrict__ e_w,
                                             const ushort_t* __restrict__ m_bf,
                                             ushort_t* __restrict__ agg_bf) {
    int node = blockIdx.x * 4 + (threadIdx.x >> 6);
    int lane = threadIdx.x & 63;
    if (node >= NN) return;
    int b = off[node], e = off[node + 1];
    const uint_t* m2 = (const uint_t*)m_bf;
    float ax = 0.f, ay = 0.f;
    int i = b;
    for (; i + 8 <= e; i += 8) {
        int s[8]; float w[8]; uint_t v[8];
#pragma unroll
        for (int q = 0; q < 8; q++) { s[q] = e_src[i + q]; w[q] = e_w[i + q]; }
#pragma unroll
        for (int q = 0; q < 8; q++) v[q] = m2[(size_t)s[q] * 64 + lane];
#pragma unroll
        for (int q = 0; q < 8; q++) {
            ax += w[q] * bf2f((ushort_t)(v[q] & 0xffffu));
            ay += w[q] * bf2f((ushort_t)(v[q] >> 16));
        }
    }
    for (; i + 4 <= e; i += 4) {
        int s[4]; float w[4]; uint_t v[4];
#pragma unroll
        for (int q = 0; q < 4; q++) { s[q] = e_src[i + q]; w[q] = e_w[i + q]; }
#pragma unroll
        for (int q = 0; q < 4; q++) v[q] = m2[(size_t)s[q] * 64 + lane];
#pragma unroll
        for (int q = 0; q < 4; q++) {
            ax += w[q] * bf2f((ushort_t)(v[q] & 0xffffu));
            ay += w[q] * bf2f((ushort_t)(v[q] >> 16));
        }
    }
    for (; i < e; i++) {
        int s = e_src[i];
        float w = e_w[i];
        uint_t v = m2[(size_t)s * 64 + lane];
        ax += w * bf2f((ushort_t)(v & 0xffffu));
        ay += w * bf2f((ushort_t)(v >> 16));
    }
    uint_t packed = (uint_t)f2bf(ax) | ((uint_t)f2bf(ay) << 16);
    ((uint_t*)agg_bf)[(size_t)node * 64 + lane] = packed;
}

// ---------------- fused GRU cell, weight-resident waves ----------------
__global__ __launch_bounds__(256, 2) void k_gru(const ushort_t* __restrict__ agg_bf,
                                                const ushort_t* __restrict__ hbf_in,
                                                ushort_t* __restrict__ hbf_out,
                                                const float* __restrict__ h_in,
                                                float* __restrict__ h_out,
                                                const ushort_t* __restrict__ wx_pk,
                                                const ushort_t* __restrict__ wh_pk,
                                                const float* __restrict__ b_ih,
                                                const float* __restrict__ b_hh) {
    int wid = (blockIdx.x * 256 + threadIdx.x) >> 6;
    int l = threadIdx.x & 63;
    int c0 = wid & 7;
    int chunk = wid >> 3;
    int lr = l & 15, lg = l >> 4;

    bf16x8 BX[12], BH[12];
    {
        const bf16x8* px = (const bf16x8*)wx_pk + (size_t)c0 * 12 * 64 + l;
        const bf16x8* ph = (const bf16x8*)wh_pk + (size_t)c0 * 12 * 64 + l;
#pragma unroll
        for (int f = 0; f < 12; f++) { BX[f] = px[f * 64]; BH[f] = ph[f * 64]; }
    }
    int c = c0 * 16 + lr;
    float bxr = b_ih[c], bxz = b_ih[128 + c], bxn = b_ih[256 + c];
    float bhr = b_hh[c], bhz = b_hh[128 + c], bhn = b_hh[256 + c];

    for (int it = 0; it < G_RG; it++) {
        int rg = chunk * G_RG + it;
        if (rg >= NRG) break;
        int n0 = rg * 16;
        const short* ap = (const short*)agg_bf + (size_t)(n0 + lr) * CC + lg * 8;
        const short* hp = (const short*)hbf_in + (size_t)(n0 + lr) * CC + lg * 8;
        bf16x8 a[4], hf[4];
#pragma unroll
        for (int s = 0; s < 4; s++) {
            a[s] = *(const bf16x8*)(ap + s * 32);
            hf[s] = *(const bf16x8*)(hp + s * 32);
        }
        float hv[4];
#pragma unroll
        for (int j = 0; j < 4; j++) hv[j] = h_in[(size_t)(n0 + lg * 4 + j) * CC + c];

        f32x4 r0 = {0.f,0.f,0.f,0.f}, r1 = {0.f,0.f,0.f,0.f}, r2 = {0.f,0.f,0.f,0.f};
        f32x4 r3 = {0.f,0.f,0.f,0.f}, r4 = {0.f,0.f,0.f,0.f}, r5 = {0.f,0.f,0.f,0.f};
#pragma unroll
        for (int s = 0; s < 4; s++) {
            r0 = __builtin_amdgcn_mfma_f32_16x16x32_bf16(a[s], BX[s], r0, 0, 0, 0);
            r1 = __builtin_amdgcn_mfma_f32_16x16x32_bf16(a[s], BX[4 + s], r1, 0, 0, 0);
            r2 = __builtin_amdgcn_mfma_f32_16x16x32_bf16(a[s], BX[8 + s], r2, 0, 0, 0);
            r3 = __builtin_amdgcn_mfma_f32_16x16x32_bf16(hf[s], BH[s], r3, 0, 0, 0);
            r4 = __builtin_amdgcn_mfma_f32_16x16x32_bf16(hf[s], BH[4 + s], r4, 0, 0, 0);
            r5 = __builtin_amdgcn_mfma_f32_16x16x32_bf16(hf[s], BH[8 + s], r5, 0, 0, 0);
        }
#pragma unroll
        for (int j = 0; j < 4; j++) {
            size_t row = (size_t)(n0 + lg * 4 + j);
            float rg_ = 1.f / (1.f + expf(-(r0[j] + bxr + r3[j] + bhr)));
            float zg = 1.f / (1.f + expf(-(r1[j] + bxz + r4[j] + bhz)));
            float ng = tanhf(r2[j] + bxn + rg_ * (r5[j] + bhn));
            float hn2 = (1.f - zg) * ng + zg * hv[j];
            h_out[row * CC + c] = hn2;
            hbf_out[row * CC + c] = f2bf(hn2);
        }
    }
}

// ---------------- fused MLP + log_softmax ----------------
__global__ __launch_bounds__(256) void k_mlp(const float* __restrict__ h,
                                             const float* __restrict__ w0, const float* __restrict__ b0,
                                             const float* __restrict__ w1, const float* __restrict__ b1,
                                             const float* __restrict__ w2, const float* __restrict__ b2,
                                             const float* __restrict__ w3, const float* __restrict__ b3,
                                             float* __restrict__ out) {
    __shared__ float w0s[32 * 128];
    __shared__ float w1s[32 * 32];
    __shared__ float w2s[32 * 32];
    __shared__ float w3s[7 * 32];
    __shared__ float bs[104];
    __shared__ float hs[256][33];
    int t = threadIdx.x;
    for (int i = t; i < 4096; i += 256) w0s[i] = w0[i];
    for (int i = t; i < 1024; i += 256) { w1s[i] = w1[i]; w2s[i] = w2[i]; }
    for (int i = t; i < 224; i += 256) w3s[i] = w3[i];
    if (t < 32) { bs[t] = b0[t]; bs[32 + t] = b1[t]; bs[64 + t] = b2[t]; }
    if (t < 7) bs[96 + t] = b3[t];

    int row = blockIdx.x * 256 + t;
    float acc0[32];
#pragma unroll
    for (int j = 0; j < 32; j++) acc0[j] = 0.f;

    for (int k0 = 0; k0 < 128; k0 += 32) {
        __syncthreads();
#pragma unroll
        for (int it = 0; it < 8; it++) {
            int idx = it * 256 + t;
            int r = idx >> 3, cq = idx & 7;
            int grow = blockIdx.x * 256 + r;
            float4 v = make_float4(0.f, 0.f, 0.f, 0.f);
            if (grow < NN) v = ((const float4*)h)[(size_t)grow * 32 + (k0 >> 2) + cq];
            hs[r][cq * 4 + 0] = v.x;
            hs[r][cq * 4 + 1] = v.y;
            hs[r][cq * 4 + 2] = v.z;
            hs[r][cq * 4 + 3] = v.w;
        }
        __syncthreads();
        for (int kk = 0; kk < 32; kk++) {
            float xk = hs[t][kk];
#pragma unroll
            for (int j = 0; j < 32; j++) acc0[j] += xk * w0s[j * 128 + k0 + kk];
        }
    }
    float v0[32];
#pragma unroll
    for (int j = 0; j < 32; j++) v0[j] = tanhf(acc0[j] + bs[j]);
    float v1[32];
#pragma unroll
    for (int j = 0; j < 32; j++) {
        float s = bs[32 + j];
#pragma unroll
        for (int k = 0; k < 32; k++) s += w1s[j * 32 + k] * v0[k];
        v1[j] = tanhf(s);
    }
    float v2[32];
#pragma unroll
    for (int j = 0; j < 32; j++) {
        float s = bs[64 + j];
#pragma unroll
        for (int k = 0; k < 32; k++) s += w2s[j * 32 + k] * v1[k];
        v2[j] = tanhf(s);
    }
    float y3[7];
#pragma unroll
    for (int j = 0; j < 7; j++) {
        float s = bs[96 + j];
#pragma unroll
        for (int k = 0; k < 32; k++) s += w3s[j * 32 + k] * v2[k];
        y3[j] = s;
    }
    float mx = y3[0];
#pragma unroll
    for (int j = 1; j < 7; j++) mx = fmaxf(mx, y3[j]);
    float se = 0.f;
#pragma unroll
    for (int j = 0; j < 7; j++) se += expf(y3[j] - mx);
    float lse = mx + logf(se);
    if (row < NN) {
#pragma unroll
        for (int j = 0; j < 7; j++) out[(size_t)row * 7 + j] = y3[j] - lse;
    }
}

extern "C" void kernel_launch(void* const* d_in, const int* in_sizes, int n_in,
                              void* d_out, int out_size, void* d_ws, size_t ws_size,
                              hipStream_t stream) {
    const float* x   = (const float*)d_in[0];
    const int*   ei  = (const int*)d_in[1];
    const float* ew  = (const float*)d_in[2];
    const float* cw  = (const float*)d_in[3];
    const float* wih = (const float*)d_in[4];
    const float* whh = (const float*)d_in[5];
    const float* bih = (const float*)d_in[6];
    const float* bhh = (const float*)d_in[7];
    const float* w0 = (const float*)d_in[8];
    const float* b0 = (const float*)d_in[9];
    const float* w1 = (const float*)d_in[10];
    const float* b1 = (const float*)d_in[11];
    const float* w2 = (const float*)d_in[12];
    const float* b2 = (const float*)d_in[13];
    const float* w3 = (const float*)d_in[14];
    const float* b3 = (const float*)d_in[15];
    float* out = (float*)d_out;

    float*    h     = (float*)d_ws;
    ushort_t* hbf0  = (ushort_t*)(h + (size_t)NN * CC);
    ushort_t* hbf1  = hbf0 + (size_t)NN * CC;
    ushort_t* m_bf  = hbf1 + (size_t)NN * CC;
    ushort_t* agg_bf= m_bf + (size_t)NN * CC;
    ushort_t* wx_pk = agg_bf + (size_t)NN * CC;
    ushort_t* wh_pk = wx_pk + 3 * CC * CC;
    ushort_t* cw_pk = wh_pk + 3 * CC * CC;
    float*    e_w   = (float*)(cw_pk + 3 * CC * CC);
    int*      e_src = (int*)(e_w + NE);
    int*      off   = e_src + NE;                 // NN+1
    int*      deg   = off + (NN + 1);             // NN
    int*      cursor= deg + NN;                   // NN
    int*      bsum  = cursor + NN;                // SCAN_B
    int*      bofs  = bsum + SCAN_B;              // SCAN_B

    const int* src = ei;
    const int* dst = ei + NE;

    k_cvt<<<(NN * CC) / 1024, 256, 0, stream>>>(x, hbf0);
    k_wpack<<<192, 256, 0, stream>>>(wih, wx_pk);
    k_wpack<<<192, 256, 0, stream>>>(whh, wh_pk);
    k_cpack<<<192, 256, 0, stream>>>(cw, cw_pk);

    // CSR build (once per call)
    hipMemsetAsync(deg, 0, NN * sizeof(int), stream);
    k_count<<<(NE + 255) / 256, 256, 0, stream>>>(dst, deg);
    k_scan1<<<SCAN_B, 256, 0, stream>>>(deg, off, bsum);
    k_scan2<<<1, 256, 0, stream>>>(bsum, bofs, off);
    k_scan3<<<SCAN_B, 256, 0, stream>>>(off, bofs, cursor);
    k_fill<<<(NE + 255) / 256, 256, 0, stream>>>(src, dst, ew, cursor, e_src, e_w);

    const int conv_waves = 4 * ((NRG + G_RG - 1) / G_RG);
    const int conv_blk = (conv_waves + 3) / 4;
    const int gru_waves = 8 * ((NRG + G_RG - 1) / G_RG);
    const int gru_blk = (gru_waves + 3) / 4;

    ushort_t* hin = hbf0;
    ushort_t* hout = hbf1;
    for (int l = 0; l < NL; l++) {
        k_conv<<<conv_blk, 256, 0, stream>>>(hin, cw_pk + (size_t)l * CC * CC, m_bf);
        k_agg<<<(NN + 3) / 4, 256, 0, stream>>>(off, e_src, e_w, m_bf, agg_bf);
        k_gru<<<gru_blk, 256, 0, stream>>>(agg_bf, hin, hout,
                                           (l == 0) ? x : h, h, wx_pk, wh_pk, bih, bhh);
        ushort_t* tmp = hin; hin = hout; hout = tmp;
    }
    k_mlp<<<(NN + 255) / 256, 256, 0, stream>>>(h, w0, b0, w1, b1, w2, b2, w3, b3, out);
}

// Round 6
// 354.784 us; speedup vs baseline: 11.7526x; 1.1179x over previous
//
#include <hip/hip_runtime.h>
#include <hip/hip_bf16.h>
#include <math.h>

#define NN 50000
#define NE 600000
#define CC 128
#define NL 3
#define NRG (NN / 16)      // 3125 row-groups
#define G_RG 8             // row-groups per weight-resident wave
#define SCAN_B 196         // ceil(NN/256)

typedef __attribute__((ext_vector_type(8))) short bf16x8;
typedef __attribute__((ext_vector_type(4))) float f32x4;
typedef unsigned short ushort_t;
typedef unsigned int uint_t;

__device__ inline ushort_t f2bf(float f) {
    __hip_bfloat16 b = __float2bfloat16(f);
    return *reinterpret_cast<ushort_t*>(&b);
}
__device__ inline float bf2f(ushort_t u) {
    return __uint_as_float(((uint_t)u) << 16);
}

// ---------------- x -> hbf0 (bf16) ----------------
__global__ __launch_bounds__(256) void k_cvt(const float* __restrict__ x,
                                             ushort_t* __restrict__ h_bf) {
    size_t i = (size_t)blockIdx.x * 256 + threadIdx.x;
    float4 v = ((const float4*)x)[i];
    ushort4 u;
    u.x = f2bf(v.x); u.y = f2bf(v.y); u.z = f2bf(v.z); u.w = f2bf(v.w);
    ((ushort4*)h_bf)[i] = u;
}

// ---------------- GRU weights -> packed bf16 fragments ----------------
__global__ __launch_bounds__(256) void k_wpack(const float* __restrict__ W,
                                               ushort_t* __restrict__ pk) {
    int tid = blockIdx.x * 256 + threadIdx.x;    // 49152
    int e = tid & 7;
    int l = (tid >> 3) & 63;
    int s = (tid >> 9) & 3;
    int rest = tid >> 11;                        // c0*3+g
    int g = rest % 3, c0 = rest / 3;
    int row = g * 128 + c0 * 16 + (l & 15);
    int col = s * 32 + (l >> 4) * 8 + e;
    pk[tid] = f2bf(W[row * 128 + col]);
}

// ---------------- conv weights -> packed bf16 fragments (3 layers) ----------------
__global__ __launch_bounds__(256) void k_cpack(const float* __restrict__ cw,
                                               ushort_t* __restrict__ pk) {
    int tid = blockIdx.x * 256 + threadIdx.x;    // 49152
    int e = tid & 7;
    int l = (tid >> 3) & 63;
    int s = (tid >> 9) & 3;
    int rest = tid >> 11;                        // layer*8 + c0
    int c0 = rest & 7, layer = rest >> 3;
    int c = c0 * 16 + (l & 15);
    int k = s * 32 + (l >> 4) * 8 + e;
    pk[tid] = f2bf(cw[layer * 16384 + k * 128 + c]);
}

// ---------------- MLP weights -> packed bf16 fragments ----------------
// layout (ushort): w0 frags [0,4096): F=c0*4+s; w1 [4096,5120): F=c0;
//                  w2 [5120,6144): F=c0; w3 [6144,6656): zero-padded rows>=7
__global__ __launch_bounds__(256) void k_mpack(const float* __restrict__ w0,
                                               const float* __restrict__ w1,
                                               const float* __restrict__ w2,
                                               const float* __restrict__ w3,
                                               ushort_t* __restrict__ pk) {
    int tid = blockIdx.x * 256 + threadIdx.x;    // 6656
    if (tid >= 6656) return;
    int e = tid & 7;
    int l = (tid >> 3) & 63;
    int lr = l & 15, lg = l >> 4;
    if (tid < 4096) {
        int s = (tid >> 9) & 3;
        int c0 = tid >> 11;
        pk[tid] = f2bf(w0[(c0 * 16 + lr) * 128 + s * 32 + lg * 8 + e]);
    } else if (tid < 5120) {
        int c0 = (tid - 4096) >> 9;
        pk[tid] = f2bf(w1[(c0 * 16 + lr) * 32 + lg * 8 + e]);
    } else if (tid < 6144) {
        int c0 = (tid - 5120) >> 9;
        pk[tid] = f2bf(w2[(c0 * 16 + lr) * 32 + lg * 8 + e]);
    } else {
        pk[tid] = (lr < 7) ? f2bf(w3[lr * 32 + lg * 8 + e]) : (ushort_t)0;
    }
}

// ---------------- CSR build ----------------
__global__ __launch_bounds__(256) void k_count(const int* __restrict__ dst,
                                               int* __restrict__ deg) {
    int e = blockIdx.x * 256 + threadIdx.x;
    if (e < NE) atomicAdd(&deg[dst[e]], 1);
}

__global__ __launch_bounds__(256) void k_scan1(const int* __restrict__ deg,
                                               int* __restrict__ off,
                                               int* __restrict__ bsum) {
    __shared__ int sm[256];
    int t = threadIdx.x, i = blockIdx.x * 256 + t;
    int v = (i < NN) ? deg[i] : 0;
    sm[t] = v;
    __syncthreads();
#pragma unroll
    for (int ofs = 1; ofs < 256; ofs <<= 1) {
        int u = (t >= ofs) ? sm[t - ofs] : 0;
        __syncthreads();
        sm[t] += u;
        __syncthreads();
    }
    if (i < NN) off[i] = sm[t] - v;
    if (t == 255) bsum[blockIdx.x] = sm[255];
}

__global__ __launch_bounds__(256) void k_scan2(const int* __restrict__ bsum,
                                               int* __restrict__ bofs,
                                               int* __restrict__ off) {
    __shared__ int sm[256];
    int t = threadIdx.x;
    int v = (t < SCAN_B) ? bsum[t] : 0;
    sm[t] = v;
    __syncthreads();
#pragma unroll
    for (int ofs = 1; ofs < 256; ofs <<= 1) {
        int u = (t >= ofs) ? sm[t - ofs] : 0;
        __syncthreads();
        sm[t] += u;
        __syncthreads();
    }
    if (t < SCAN_B) bofs[t] = sm[t] - v;
    if (t == 255) off[NN] = sm[255];
}

__global__ __launch_bounds__(256) void k_scan3(int* __restrict__ off,
                                               const int* __restrict__ bofs,
                                               int* __restrict__ cursor) {
    int t = threadIdx.x, i = blockIdx.x * 256 + t;
    if (i < NN) {
        int o = off[i] + bofs[blockIdx.x];
        off[i] = o;
        cursor[i] = o;
    }
}

__global__ __launch_bounds__(256) void k_fill(const int* __restrict__ src,
                                              const int* __restrict__ dst,
                                              const float* __restrict__ ew,
                                              int* __restrict__ cursor,
                                              int* __restrict__ e_src,
                                              float* __restrict__ e_w) {
    int e = blockIdx.x * 256 + threadIdx.x;
    if (e >= NE) return;
    int d = dst[e];
    int p = atomicAdd(&cursor[d], 1);
    e_src[p] = src[e];
    e_w[p] = ew[e];
}

// ---------------- m_bf = bf16( h_bf @ W ), weight-resident waves ----------------
__global__ __launch_bounds__(256, 2) void k_conv(const ushort_t* __restrict__ h_bf,
                                                 const ushort_t* __restrict__ cw_pk,
                                                 ushort_t* __restrict__ m_bf) {
    int wid = (blockIdx.x * 256 + threadIdx.x) >> 6;
    int l = threadIdx.x & 63;
    int lr = l & 15, lg = l >> 4;
    int c0g = wid & 3;
    int chunk = wid >> 2;

    bf16x8 B[2][4];
    {
        const bf16x8* pw = (const bf16x8*)cw_pk;
#pragma unroll
        for (int p = 0; p < 2; p++)
#pragma unroll
            for (int s = 0; s < 4; s++)
                B[p][s] = pw[(size_t)(((c0g + 4 * p) * 4 + s) * 64) + l];
    }
    int c_lo = c0g * 16 + lr;

    for (int it = 0; it < G_RG; it++) {
        int rg = chunk * G_RG + it;
        if (rg >= NRG) break;
        int n0 = rg * 16;
        const short* ap = (const short*)h_bf + (size_t)(n0 + lr) * CC + lg * 8;
        bf16x8 a[4];
#pragma unroll
        for (int s = 0; s < 4; s++) a[s] = *(const bf16x8*)(ap + s * 32);
        f32x4 acc0 = {0.f,0.f,0.f,0.f}, acc1 = {0.f,0.f,0.f,0.f};
#pragma unroll
        for (int s = 0; s < 4; s++) {
            acc0 = __builtin_amdgcn_mfma_f32_16x16x32_bf16(a[s], B[0][s], acc0, 0, 0, 0);
            acc1 = __builtin_amdgcn_mfma_f32_16x16x32_bf16(a[s], B[1][s], acc1, 0, 0, 0);
        }
#pragma unroll
        for (int j = 0; j < 4; j++) {
            size_t row = (size_t)(n0 + lg * 4 + j) * CC;
            m_bf[row + c_lo] = f2bf(acc0[j]);
            m_bf[row + c_lo + 64] = f2bf(acc1[j]);
        }
    }
}

// ---------------- agg_bf[n] = bf16( sum w_e * m_bf[src_e] ), 8x unrolled gather ----------------
__global__ __launch_bounds__(256) void k_agg(const int* __restrict__ off,
                                             const int* __restrict__ e_src,
                                             const float* __restrict__ e_w,
                                             const ushort_t* __restrict__ m_bf,
                                             ushort_t* __restrict__ agg_bf) {
    int node = blockIdx.x * 4 + (threadIdx.x >> 6);
    int lane = threadIdx.x & 63;
    if (node >= NN) return;
    int b = off[node], e = off[node + 1];
    const uint_t* m2 = (const uint_t*)m_bf;
    float ax = 0.f, ay = 0.f;
    int i = b;
    for (; i + 8 <= e; i += 8) {
        int s[8]; float w[8]; uint_t v[8];
#pragma unroll
        for (int q = 0; q < 8; q++) { s[q] = e_src[i + q]; w[q] = e_w[i + q]; }
#pragma unroll
        for (int q = 0; q < 8; q++) v[q] = m2[(size_t)s[q] * 64 + lane];
#pragma unroll
        for (int q = 0; q < 8; q++) {
            ax += w[q] * bf2f((ushort_t)(v[q] & 0xffffu));
            ay += w[q] * bf2f((ushort_t)(v[q] >> 16));
        }
    }
    for (; i + 4 <= e; i += 4) {
        int s[4]; float w[4]; uint_t v[4];
#pragma unroll
        for (int q = 0; q < 4; q++) { s[q] = e_src[i + q]; w[q] = e_w[i + q]; }
#pragma unroll
        for (int q = 0; q < 4; q++) v[q] = m2[(size_t)s[q] * 64 + lane];
#pragma unroll
        for (int q = 0; q < 4; q++) {
            ax += w[q] * bf2f((ushort_t)(v[q] & 0xffffu));
            ay += w[q] * bf2f((ushort_t)(v[q] >> 16));
        }
    }
    for (; i < e; i++) {
        int s = e_src[i];
        float w = e_w[i];
        uint_t v = m2[(size_t)s * 64 + lane];
        ax += w * bf2f((ushort_t)(v & 0xffffu));
        ay += w * bf2f((ushort_t)(v >> 16));
    }
    uint_t packed = (uint_t)f2bf(ax) | ((uint_t)f2bf(ay) << 16);
    ((uint_t*)agg_bf)[(size_t)node * 64 + lane] = packed;
}

// ---------------- fused GRU cell, weight-resident waves ----------------
__global__ __launch_bounds__(256, 2) void k_gru(const ushort_t* __restrict__ agg_bf,
                                                const ushort_t* __restrict__ hbf_in,
                                                ushort_t* __restrict__ hbf_out,
                                                const float* __restrict__ h_in,
                                                float* __restrict__ h_out,
                                                const ushort_t* __restrict__ wx_pk,
                                                const ushort_t* __restrict__ wh_pk,
                                                const float* __restrict__ b_ih,
                                                const float* __restrict__ b_hh,
                                                int store_f32) {
    int wid = (blockIdx.x * 256 + threadIdx.x) >> 6;
    int l = threadIdx.x & 63;
    int c0 = wid & 7;
    int chunk = wid >> 3;
    int lr = l & 15, lg = l >> 4;

    bf16x8 BX[12], BH[12];
    {
        const bf16x8* px = (const bf16x8*)wx_pk + (size_t)c0 * 12 * 64 + l;
        const bf16x8* ph = (const bf16x8*)wh_pk + (size_t)c0 * 12 * 64 + l;
#pragma unroll
        for (int f = 0; f < 12; f++) { BX[f] = px[f * 64]; BH[f] = ph[f * 64]; }
    }
    int c = c0 * 16 + lr;
    float bxr = b_ih[c], bxz = b_ih[128 + c], bxn = b_ih[256 + c];
    float bhr = b_hh[c], bhz = b_hh[128 + c], bhn = b_hh[256 + c];

    for (int it = 0; it < G_RG; it++) {
        int rg = chunk * G_RG + it;
        if (rg >= NRG) break;
        int n0 = rg * 16;
        const short* ap = (const short*)agg_bf + (size_t)(n0 + lr) * CC + lg * 8;
        const short* hp = (const short*)hbf_in + (size_t)(n0 + lr) * CC + lg * 8;
        bf16x8 a[4], hf[4];
#pragma unroll
        for (int s = 0; s < 4; s++) {
            a[s] = *(const bf16x8*)(ap + s * 32);
            hf[s] = *(const bf16x8*)(hp + s * 32);
        }
        float hv[4];
#pragma unroll
        for (int j = 0; j < 4; j++) hv[j] = h_in[(size_t)(n0 + lg * 4 + j) * CC + c];

        f32x4 r0 = {0.f,0.f,0.f,0.f}, r1 = {0.f,0.f,0.f,0.f}, r2 = {0.f,0.f,0.f,0.f};
        f32x4 r3 = {0.f,0.f,0.f,0.f}, r4 = {0.f,0.f,0.f,0.f}, r5 = {0.f,0.f,0.f,0.f};
#pragma unroll
        for (int s = 0; s < 4; s++) {
            r0 = __builtin_amdgcn_mfma_f32_16x16x32_bf16(a[s], BX[s], r0, 0, 0, 0);
            r1 = __builtin_amdgcn_mfma_f32_16x16x32_bf16(a[s], BX[4 + s], r1, 0, 0, 0);
            r2 = __builtin_amdgcn_mfma_f32_16x16x32_bf16(a[s], BX[8 + s], r2, 0, 0, 0);
            r3 = __builtin_amdgcn_mfma_f32_16x16x32_bf16(hf[s], BH[s], r3, 0, 0, 0);
            r4 = __builtin_amdgcn_mfma_f32_16x16x32_bf16(hf[s], BH[4 + s], r4, 0, 0, 0);
            r5 = __builtin_amdgcn_mfma_f32_16x16x32_bf16(hf[s], BH[8 + s], r5, 0, 0, 0);
        }
#pragma unroll
        for (int j = 0; j < 4; j++) {
            size_t row = (size_t)(n0 + lg * 4 + j);
            float rg_ = 1.f / (1.f + expf(-(r0[j] + bxr + r3[j] + bhr)));
            float zg = 1.f / (1.f + expf(-(r1[j] + bxz + r4[j] + bhz)));
            float ng = tanhf(r2[j] + bxn + rg_ * (r5[j] + bhn));
            float hn2 = (1.f - zg) * ng + zg * hv[j];
            if (store_f32) h_out[row * CC + c] = hn2;
            hbf_out[row * CC + c] = f2bf(hn2);
        }
    }
}

// ---------------- MFMA MLP + log_softmax: wave per 16 rows ----------------
__global__ __launch_bounds__(256, 2) void k_mlp(const ushort_t* __restrict__ hbf,
                                                const ushort_t* __restrict__ wm_pk,
                                                const float* __restrict__ b0,
                                                const float* __restrict__ b1,
                                                const float* __restrict__ b2,
                                                const float* __restrict__ b3,
                                                float* __restrict__ out) {
    __shared__ short vt[4][16][40];    // activation tile, stride 40 shorts (80B, 16B-aligned, low-conflict)
    __shared__ float yt[4][16][8];     // logits tile for log-softmax finish
    int wid = (blockIdx.x * 256 + threadIdx.x) >> 6;
    int wq = threadIdx.x >> 6;
    int l = threadIdx.x & 63;
    int lr = l & 15, lg = l >> 4;

    // resident weight fragments
    bf16x8 W0[2][4], W1[2], W2[2], W3;
    {
        const bf16x8* pw = (const bf16x8*)wm_pk;
#pragma unroll
        for (int c0 = 0; c0 < 2; c0++)
#pragma unroll
            for (int s = 0; s < 4; s++) W0[c0][s] = pw[(c0 * 4 + s) * 64 + l];
#pragma unroll
        for (int c0 = 0; c0 < 2; c0++) {
            W1[c0] = pw[512 + c0 * 64 + l];
            W2[c0] = pw[640 + c0 * 64 + l];
        }
        W3 = pw[768 + l];
    }
    float b0v[2] = {b0[lr], b0[16 + lr]};
    float b1v[2] = {b1[lr], b1[16 + lr]};
    float b2v[2] = {b2[lr], b2[16 + lr]};
    float b3v = (lr < 7) ? b3[lr] : 0.f;

    if (wid >= NRG) return;
    int n0 = wid * 16;

    // layer 0: [16,128] @ w0^T -> [16,32]
    bf16x8 a[4];
    {
        const short* ap = (const short*)hbf + (size_t)(n0 + lr) * CC + lg * 8;
#pragma unroll
        for (int s = 0; s < 4; s++) a[s] = *(const bf16x8*)(ap + s * 32);
    }
#pragma unroll
    for (int c0 = 0; c0 < 2; c0++) {
        f32x4 acc = {0.f, 0.f, 0.f, 0.f};
#pragma unroll
        for (int s = 0; s < 4; s++)
            acc = __builtin_amdgcn_mfma_f32_16x16x32_bf16(a[s], W0[c0][s], acc, 0, 0, 0);
#pragma unroll
        for (int j = 0; j < 4; j++)
            vt[wq][lg * 4 + j][c0 * 16 + lr] = (short)f2bf(tanhf(acc[j] + b0v[c0]));
    }
    // layer 1: [16,32] @ w1^T
    {
        bf16x8 av = *(const bf16x8*)&vt[wq][lr][lg * 8];
        f32x4 acc[2];
#pragma unroll
        for (int c0 = 0; c0 < 2; c0++) {
            f32x4 z = {0.f, 0.f, 0.f, 0.f};
            acc[c0] = __builtin_amdgcn_mfma_f32_16x16x32_bf16(av, W1[c0], z, 0, 0, 0);
        }
#pragma unroll
        for (int c0 = 0; c0 < 2; c0++)
#pragma unroll
            for (int j = 0; j < 4; j++)
                vt[wq][lg * 4 + j][c0 * 16 + lr] = (short)f2bf(tanhf(acc[c0][j] + b1v[c0]));
    }
    // layer 2
    {
        bf16x8 av = *(const bf16x8*)&vt[wq][lr][lg * 8];
        f32x4 acc[2];
#pragma unroll
        for (int c0 = 0; c0 < 2; c0++) {
            f32x4 z = {0.f, 0.f, 0.f, 0.f};
            acc[c0] = __builtin_amdgcn_mfma_f32_16x16x32_bf16(av, W2[c0], z, 0, 0, 0);
        }
#pragma unroll
        for (int c0 = 0; c0 < 2; c0++)
#pragma unroll
            for (int j = 0; j < 4; j++)
                vt[wq][lg * 4 + j][c0 * 16 + lr] = (short)f2bf(tanhf(acc[c0][j] + b2v[c0]));
    }
    // layer 3: [16,32] @ w3^T -> [16,7]
    {
        bf16x8 av = *(const bf16x8*)&vt[wq][lr][lg * 8];
        f32x4 z = {0.f, 0.f, 0.f, 0.f};
        f32x4 acc = __builtin_amdgcn_mfma_f32_16x16x32_bf16(av, W3, z, 0, 0, 0);
        if (lr < 7) {
#pragma unroll
            for (int j = 0; j < 4; j++) yt[wq][lg * 4 + j][lr] = acc[j] + b3v;
        }
    }
    // log-softmax finish: lanes 0..15 each own one row
    __builtin_amdgcn_s_waitcnt(0);   // lgkmcnt(0): wave-internal LDS drain
    if (l < 16) {
        float y[7];
#pragma unroll
        for (int j = 0; j < 7; j++) y[j] = yt[wq][l][j];
        float mx = y[0];
#pragma unroll
        for (int j = 1; j < 7; j++) mx = fmaxf(mx, y[j]);
        float se = 0.f;
#pragma unroll
        for (int j = 0; j < 7; j++) se += expf(y[j] - mx);
        float lse = mx + logf(se);
#pragma unroll
        for (int j = 0; j < 7; j++) out[(size_t)(n0 + l) * 7 + j] = y[j] - lse;
    }
}

extern "C" void kernel_launch(void* const* d_in, const int* in_sizes, int n_in,
                              void* d_out, int out_size, void* d_ws, size_t ws_size,
                              hipStream_t stream) {
    const float* x   = (const float*)d_in[0];
    const int*   ei  = (const int*)d_in[1];
    const float* ew  = (const float*)d_in[2];
    const float* cw  = (const float*)d_in[3];
    const float* wih = (const float*)d_in[4];
    const float* whh = (const float*)d_in[5];
    const float* bih = (const float*)d_in[6];
    const float* bhh = (const float*)d_in[7];
    const float* w0 = (const float*)d_in[8];
    const float* b0 = (const float*)d_in[9];
    const float* w1 = (const float*)d_in[10];
    const float* b1 = (const float*)d_in[11];
    const float* w2 = (const float*)d_in[12];
    const float* b2 = (const float*)d_in[13];
    const float* w3 = (const float*)d_in[14];
    const float* b3 = (const float*)d_in[15];
    float* out = (float*)d_out;

    float*    h     = (float*)d_ws;
    ushort_t* hbf0  = (ushort_t*)(h + (size_t)NN * CC);
    ushort_t* hbf1  = hbf0 + (size_t)NN * CC;
    ushort_t* m_bf  = hbf1 + (size_t)NN * CC;
    ushort_t* agg_bf= m_bf + (size_t)NN * CC;
    ushort_t* wx_pk = agg_bf + (size_t)NN * CC;
    ushort_t* wh_pk = wx_pk + 3 * CC * CC;
    ushort_t* cw_pk = wh_pk + 3 * CC * CC;
    ushort_t* wm_pk = cw_pk + 3 * CC * CC;        // 6656 shorts
    float*    e_w   = (float*)(wm_pk + 6656);
    int*      e_src = (int*)(e_w + NE);
    int*      off   = e_src + NE;                 // NN+1
    int*      deg   = off + (NN + 1);             // NN
    int*      cursor= deg + NN;                   // NN
    int*      bsum  = cursor + NN;                // SCAN_B
    int*      bofs  = bsum + SCAN_B;              // SCAN_B

    const int* src = ei;
    const int* dst = ei + NE;

    k_cvt<<<(NN * CC) / 1024, 256, 0, stream>>>(x, hbf0);
    k_wpack<<<192, 256, 0, stream>>>(wih, wx_pk);
    k_wpack<<<192, 256, 0, stream>>>(whh, wh_pk);
    k_cpack<<<192, 256, 0, stream>>>(cw, cw_pk);
    k_mpack<<<26, 256, 0, stream>>>(w0, w1, w2, w3, wm_pk);

    // CSR build (once per call)
    hipMemsetAsync(deg, 0, NN * sizeof(int), stream);
    k_count<<<(NE + 255) / 256, 256, 0, stream>>>(dst, deg);
    k_scan1<<<SCAN_B, 256, 0, stream>>>(deg, off, bsum);
    k_scan2<<<1, 256, 0, stream>>>(bsum, bofs, off);
    k_scan3<<<SCAN_B, 256, 0, stream>>>(off, bofs, cursor);
    k_fill<<<(NE + 255) / 256, 256, 0, stream>>>(src, dst, ew, cursor, e_src, e_w);

    const int conv_waves = 4 * ((NRG + G_RG - 1) / G_RG);
    const int conv_blk = (conv_waves + 3) / 4;
    const int gru_waves = 8 * ((NRG + G_RG - 1) / G_RG);
    const int gru_blk = (gru_waves + 3) / 4;

    ushort_t* hin = hbf0;
    ushort_t* hout = hbf1;
    for (int l = 0; l < NL; l++) {
        k_conv<<<conv_blk, 256, 0, stream>>>(hin, cw_pk + (size_t)l * CC * CC, m_bf);
        k_agg<<<(NN + 3) / 4, 256, 0, stream>>>(off, e_src, e_w, m_bf, agg_bf);
        k_gru<<<gru_blk, 256, 0, stream>>>(agg_bf, hin, hout,
                                           (l == 0) ? x : h, h, wx_pk, wh_pk, bih, bhh,
                                           (l < NL - 1) ? 1 : 0);
        ushort_t* tmp = hin; hin = hout; hout = tmp;
    }
    k_mlp<<<(NRG + 3) / 4, 256, 0, stream>>>(hin, wm_pk, b0, b1, b2, b3, out);
}

// Round 7
// 336.482 us; speedup vs baseline: 12.3918x; 1.0544x over previous
//
#include <hip/hip_runtime.h>
#include <hip/hip_bf16.h>
#include <math.h>

#define NN 50000
#define NE 600000
#define CC 128
#define NL 3
#define NRG (NN / 16)      // 3125 row-groups
#define C_RG 4             // row-groups per conv wave
#define G_RG 4             // row-groups per gru wave
#define SCAN_B 196         // ceil(NN/256)

typedef __attribute__((ext_vector_type(8))) short bf16x8;
typedef __attribute__((ext_vector_type(4))) float f32x4;
typedef unsigned short ushort_t;
typedef unsigned int uint_t;

__device__ inline ushort_t f2bf(float f) {
    __hip_bfloat16 b = __float2bfloat16(f);
    return *reinterpret_cast<ushort_t*>(&b);
}
__device__ inline float bf2f(ushort_t u) {
    return __uint_as_float(((uint_t)u) << 16);
}
// fast sigmoid: 1/(1+2^(-x*log2e)); exp2->inf for large -x handled by rcp(inf)=0
__device__ inline float fsig(float x) {
    return __builtin_amdgcn_rcpf(1.f + __builtin_amdgcn_exp2f(-1.44269504f * x));
}
// fast tanh: sign(x) * (1 - 2/(2^(2|x|*log2e)+1)); e=inf -> 1
__device__ inline float ftanh(float x) {
    float e = __builtin_amdgcn_exp2f(2.88539008f * fabsf(x));
    float t = 1.f - 2.f * __builtin_amdgcn_rcpf(e + 1.f);
    return copysignf(t, x);
}

// ---------------- x -> hbf0 (bf16) ----------------
__global__ __launch_bounds__(256) void k_cvt(const float* __restrict__ x,
                                             ushort_t* __restrict__ h_bf) {
    size_t i = (size_t)blockIdx.x * 256 + threadIdx.x;
    float4 v = ((const float4*)x)[i];
    ushort4 u;
    u.x = f2bf(v.x); u.y = f2bf(v.y); u.z = f2bf(v.z); u.w = f2bf(v.w);
    ((ushort4*)h_bf)[i] = u;
}

// ---------------- GRU weights -> packed bf16 fragments ----------------
__global__ __launch_bounds__(256) void k_wpack(const float* __restrict__ W,
                                               ushort_t* __restrict__ pk) {
    int tid = blockIdx.x * 256 + threadIdx.x;    // 49152
    int e = tid & 7;
    int l = (tid >> 3) & 63;
    int s = (tid >> 9) & 3;
    int rest = tid >> 11;                        // c0*3+g
    int g = rest % 3, c0 = rest / 3;
    int row = g * 128 + c0 * 16 + (l & 15);
    int col = s * 32 + (l >> 4) * 8 + e;
    pk[tid] = f2bf(W[row * 128 + col]);
}

// ---------------- conv weights -> packed bf16 fragments (3 layers) ----------------
__global__ __launch_bounds__(256) void k_cpack(const float* __restrict__ cw,
                                               ushort_t* __restrict__ pk) {
    int tid = blockIdx.x * 256 + threadIdx.x;    // 49152
    int e = tid & 7;
    int l = (tid >> 3) & 63;
    int s = (tid >> 9) & 3;
    int rest = tid >> 11;                        // layer*8 + c0
    int c0 = rest & 7, layer = rest >> 3;
    int c = c0 * 16 + (l & 15);
    int k = s * 32 + (l >> 4) * 8 + e;
    pk[tid] = f2bf(cw[layer * 16384 + k * 128 + c]);
}

// ---------------- MLP weights -> packed bf16 fragments ----------------
__global__ __launch_bounds__(256) void k_mpack(const float* __restrict__ w0,
                                               const float* __restrict__ w1,
                                               const float* __restrict__ w2,
                                               const float* __restrict__ w3,
                                               ushort_t* __restrict__ pk) {
    int tid = blockIdx.x * 256 + threadIdx.x;    // 6656
    if (tid >= 6656) return;
    int e = tid & 7;
    int l = (tid >> 3) & 63;
    int lr = l & 15, lg = l >> 4;
    if (tid < 4096) {
        int s = (tid >> 9) & 3;
        int c0 = tid >> 11;
        pk[tid] = f2bf(w0[(c0 * 16 + lr) * 128 + s * 32 + lg * 8 + e]);
    } else if (tid < 5120) {
        int c0 = (tid - 4096) >> 9;
        pk[tid] = f2bf(w1[(c0 * 16 + lr) * 32 + lg * 8 + e]);
    } else if (tid < 6144) {
        int c0 = (tid - 5120) >> 9;
        pk[tid] = f2bf(w2[(c0 * 16 + lr) * 32 + lg * 8 + e]);
    } else {
        pk[tid] = (lr < 7) ? f2bf(w3[lr * 32 + lg * 8 + e]) : (ushort_t)0;
    }
}

// ---------------- CSR build ----------------
__global__ __launch_bounds__(256) void k_count(const int* __restrict__ dst,
                                               int* __restrict__ deg) {
    int e = blockIdx.x * 256 + threadIdx.x;
    if (e < NE) atomicAdd(&deg[dst[e]], 1);
}

__global__ __launch_bounds__(256) void k_scan1(const int* __restrict__ deg,
                                               int* __restrict__ off,
                                               int* __restrict__ bsum) {
    __shared__ int sm[256];
    int t = threadIdx.x, i = blockIdx.x * 256 + t;
    int v = (i < NN) ? deg[i] : 0;
    sm[t] = v;
    __syncthreads();
#pragma unroll
    for (int ofs = 1; ofs < 256; ofs <<= 1) {
        int u = (t >= ofs) ? sm[t - ofs] : 0;
        __syncthreads();
        sm[t] += u;
        __syncthreads();
    }
    if (i < NN) off[i] = sm[t] - v;
    if (t == 255) bsum[blockIdx.x] = sm[255];
}

__global__ __launch_bounds__(256) void k_scan2(const int* __restrict__ bsum,
                                               int* __restrict__ bofs,
                                               int* __restrict__ off) {
    __shared__ int sm[256];
    int t = threadIdx.x;
    int v = (t < SCAN_B) ? bsum[t] : 0;
    sm[t] = v;
    __syncthreads();
#pragma unroll
    for (int ofs = 1; ofs < 256; ofs <<= 1) {
        int u = (t >= ofs) ? sm[t - ofs] : 0;
        __syncthreads();
        sm[t] += u;
        __syncthreads();
    }
    if (t < SCAN_B) bofs[t] = sm[t] - v;
    if (t == 255) off[NN] = sm[255];
}

__global__ __launch_bounds__(256) void k_scan3(int* __restrict__ off,
                                               const int* __restrict__ bofs,
                                               int* __restrict__ cursor) {
    int t = threadIdx.x, i = blockIdx.x * 256 + t;
    if (i < NN) {
        int o = off[i] + bofs[blockIdx.x];
        off[i] = o;
        cursor[i] = o;
    }
}

__global__ __launch_bounds__(256) void k_fill(const int* __restrict__ src,
                                              const int* __restrict__ dst,
                                              const float* __restrict__ ew,
                                              int* __restrict__ cursor,
                                              int* __restrict__ e_src,
                                              float* __restrict__ e_w) {
    int e = blockIdx.x * 256 + threadIdx.x;
    if (e >= NE) return;
    int d = dst[e];
    int p = atomicAdd(&cursor[d], 1);
    e_src[p] = src[e];
    e_w[p] = ew[e];
}

// ---------------- m_bf = bf16( h_bf @ W ), weight-resident waves ----------------
__global__ __launch_bounds__(256, 2) void k_conv(const ushort_t* __restrict__ h_bf,
                                                 const ushort_t* __restrict__ cw_pk,
                                                 ushort_t* __restrict__ m_bf) {
    int wid = (blockIdx.x * 256 + threadIdx.x) >> 6;
    int l = threadIdx.x & 63;
    int lr = l & 15, lg = l >> 4;
    int c0g = wid & 3;
    int chunk = wid >> 2;

    bf16x8 B[2][4];
    {
        const bf16x8* pw = (const bf16x8*)cw_pk;
#pragma unroll
        for (int p = 0; p < 2; p++)
#pragma unroll
            for (int s = 0; s < 4; s++)
                B[p][s] = pw[(size_t)(((c0g + 4 * p) * 4 + s) * 64) + l];
    }
    int c_lo = c0g * 16 + lr;

    for (int it = 0; it < C_RG; it++) {
        int rg = chunk * C_RG + it;
        if (rg >= NRG) break;
        int n0 = rg * 16;
        const short* ap = (const short*)h_bf + (size_t)(n0 + lr) * CC + lg * 8;
        bf16x8 a[4];
#pragma unroll
        for (int s = 0; s < 4; s++) a[s] = *(const bf16x8*)(ap + s * 32);
        f32x4 acc0 = {0.f,0.f,0.f,0.f}, acc1 = {0.f,0.f,0.f,0.f};
#pragma unroll
        for (int s = 0; s < 4; s++) {
            acc0 = __builtin_amdgcn_mfma_f32_16x16x32_bf16(a[s], B[0][s], acc0, 0, 0, 0);
            acc1 = __builtin_amdgcn_mfma_f32_16x16x32_bf16(a[s], B[1][s], acc1, 0, 0, 0);
        }
#pragma unroll
        for (int j = 0; j < 4; j++) {
            size_t row = (size_t)(n0 + lg * 4 + j) * CC;
            m_bf[row + c_lo] = f2bf(acc0[j]);
            m_bf[row + c_lo + 64] = f2bf(acc1[j]);
        }
    }
}

// ---------------- agg_bf[n] = bf16( sum w_e * m_bf[src_e] ), 8x unrolled gather ----------------
__global__ __launch_bounds__(256) void k_agg(const int* __restrict__ off,
                                             const int* __restrict__ e_src,
                                             const float* __restrict__ e_w,
                                             const ushort_t* __restrict__ m_bf,
                                             ushort_t* __restrict__ agg_bf) {
    int node = blockIdx.x * 4 + (threadIdx.x >> 6);
    int lane = threadIdx.x & 63;
    if (node >= NN) return;
    int b = off[node], e = off[node + 1];
    const uint_t* m2 = (const uint_t*)m_bf;
    float ax = 0.f, ay = 0.f;
    int i = b;
    for (; i + 8 <= e; i += 8) {
        int s[8]; float w[8]; uint_t v[8];
#pragma unroll
        for (int q = 0; q < 8; q++) { s[q] = e_src[i + q]; w[q] = e_w[i + q]; }
#pragma unroll
        for (int q = 0; q < 8; q++) v[q] = m2[(size_t)s[q] * 64 + lane];
#pragma unroll
        for (int q = 0; q < 8; q++) {
            ax += w[q] * bf2f((ushort_t)(v[q] & 0xffffu));
            ay += w[q] * bf2f((ushort_t)(v[q] >> 16));
        }
    }
    for (; i + 4 <= e; i += 4) {
        int s[4]; float w[4]; uint_t v[4];
#pragma unroll
        for (int q = 0; q < 4; q++) { s[q] = e_src[i + q]; w[q] = e_w[i + q]; }
#pragma unroll
        for (int q = 0; q < 4; q++) v[q] = m2[(size_t)s[q] * 64 + lane];
#pragma unroll
        for (int q = 0; q < 4; q++) {
            ax += w[q] * bf2f((ushort_t)(v[q] & 0xffffu));
            ay += w[q] * bf2f((ushort_t)(v[q] >> 16));
        }
    }
    for (; i < e; i++) {
        int s = e_src[i];
        float w = e_w[i];
        uint_t v = m2[(size_t)s * 64 + lane];
        ax += w * bf2f((ushort_t)(v & 0xffffu));
        ay += w * bf2f((ushort_t)(v >> 16));
    }
    uint_t packed = (uint_t)f2bf(ax) | ((uint_t)f2bf(ay) << 16);
    ((uint_t*)agg_bf)[(size_t)node * 64 + lane] = packed;
}

// ---------------- fused GRU cell, weight-resident waves, fast gates ----------------
__global__ __launch_bounds__(256, 2) void k_gru(const ushort_t* __restrict__ agg_bf,
                                                const ushort_t* __restrict__ hbf_in,
                                                ushort_t* __restrict__ hbf_out,
                                                const float* __restrict__ h_in,
                                                float* __restrict__ h_out,
                                                const ushort_t* __restrict__ wx_pk,
                                                const ushort_t* __restrict__ wh_pk,
                                                const float* __restrict__ b_ih,
                                                const float* __restrict__ b_hh,
                                                int store_f32) {
    int wid = (blockIdx.x * 256 + threadIdx.x) >> 6;
    int l = threadIdx.x & 63;
    int c0 = wid & 7;
    int chunk = wid >> 3;
    int lr = l & 15, lg = l >> 4;

    bf16x8 BX[12], BH[12];
    {
        const bf16x8* px = (const bf16x8*)wx_pk + (size_t)c0 * 12 * 64 + l;
        const bf16x8* ph = (const bf16x8*)wh_pk + (size_t)c0 * 12 * 64 + l;
#pragma unroll
        for (int f = 0; f < 12; f++) { BX[f] = px[f * 64]; BH[f] = ph[f * 64]; }
    }
    int c = c0 * 16 + lr;
    float bxr = b_ih[c], bxz = b_ih[128 + c], bxn = b_ih[256 + c];
    float bhr = b_hh[c], bhz = b_hh[128 + c], bhn = b_hh[256 + c];

    for (int it = 0; it < G_RG; it++) {
        int rg = chunk * G_RG + it;
        if (rg >= NRG) break;
        int n0 = rg * 16;
        const short* ap = (const short*)agg_bf + (size_t)(n0 + lr) * CC + lg * 8;
        const short* hp = (const short*)hbf_in + (size_t)(n0 + lr) * CC + lg * 8;
        bf16x8 a[4], hf[4];
#pragma unroll
        for (int s = 0; s < 4; s++) {
            a[s] = *(const bf16x8*)(ap + s * 32);
            hf[s] = *(const bf16x8*)(hp + s * 32);
        }
        float hv[4];
#pragma unroll
        for (int j = 0; j < 4; j++) hv[j] = h_in[(size_t)(n0 + lg * 4 + j) * CC + c];

        f32x4 r0 = {0.f,0.f,0.f,0.f}, r1 = {0.f,0.f,0.f,0.f}, r2 = {0.f,0.f,0.f,0.f};
        f32x4 r3 = {0.f,0.f,0.f,0.f}, r4 = {0.f,0.f,0.f,0.f}, r5 = {0.f,0.f,0.f,0.f};
#pragma unroll
        for (int s = 0; s < 4; s++) {
            r0 = __builtin_amdgcn_mfma_f32_16x16x32_bf16(a[s], BX[s], r0, 0, 0, 0);
            r1 = __builtin_amdgcn_mfma_f32_16x16x32_bf16(a[s], BX[4 + s], r1, 0, 0, 0);
            r2 = __builtin_amdgcn_mfma_f32_16x16x32_bf16(a[s], BX[8 + s], r2, 0, 0, 0);
            r3 = __builtin_amdgcn_mfma_f32_16x16x32_bf16(hf[s], BH[s], r3, 0, 0, 0);
            r4 = __builtin_amdgcn_mfma_f32_16x16x32_bf16(hf[s], BH[4 + s], r4, 0, 0, 0);
            r5 = __builtin_amdgcn_mfma_f32_16x16x32_bf16(hf[s], BH[8 + s], r5, 0, 0, 0);
        }
#pragma unroll
        for (int j = 0; j < 4; j++) {
            size_t row = (size_t)(n0 + lg * 4 + j);
            float rg_ = fsig(r0[j] + bxr + r3[j] + bhr);
            float zg = fsig(r1[j] + bxz + r4[j] + bhz);
            float ng = ftanh(r2[j] + bxn + rg_ * (r5[j] + bhn));
            float hn2 = (1.f - zg) * ng + zg * hv[j];
            if (store_f32) h_out[row * CC + c] = hn2;
            hbf_out[row * CC + c] = f2bf(hn2);
        }
    }
}

// ---------------- MFMA MLP + log_softmax: wave per 16 rows ----------------
__global__ __launch_bounds__(256, 2) void k_mlp(const ushort_t* __restrict__ hbf,
                                                const ushort_t* __restrict__ wm_pk,
                                                const float* __restrict__ b0,
                                                const float* __restrict__ b1,
                                                const float* __restrict__ b2,
                                                const float* __restrict__ b3,
                                                float* __restrict__ out) {
    __shared__ short vt[4][16][40];
    __shared__ float yt[4][16][8];
    int wid = (blockIdx.x * 256 + threadIdx.x) >> 6;
    int wq = threadIdx.x >> 6;
    int l = threadIdx.x & 63;
    int lr = l & 15, lg = l >> 4;

    bf16x8 W0[2][4], W1[2], W2[2], W3;
    {
        const bf16x8* pw = (const bf16x8*)wm_pk;
#pragma unroll
        for (int c0 = 0; c0 < 2; c0++)
#pragma unroll
            for (int s = 0; s < 4; s++) W0[c0][s] = pw[(c0 * 4 + s) * 64 + l];
#pragma unroll
        for (int c0 = 0; c0 < 2; c0++) {
            W1[c0] = pw[512 + c0 * 64 + l];
            W2[c0] = pw[640 + c0 * 64 + l];
        }
        W3 = pw[768 + l];
    }
    float b0v[2] = {b0[lr], b0[16 + lr]};
    float b1v[2] = {b1[lr], b1[16 + lr]};
    float b2v[2] = {b2[lr], b2[16 + lr]};
    float b3v = (lr < 7) ? b3[lr] : 0.f;

    if (wid >= NRG) return;
    int n0 = wid * 16;

    bf16x8 a[4];
    {
        const short* ap = (const short*)hbf + (size_t)(n0 + lr) * CC + lg * 8;
#pragma unroll
        for (int s = 0; s < 4; s++) a[s] = *(const bf16x8*)(ap + s * 32);
    }
#pragma unroll
    for (int c0 = 0; c0 < 2; c0++) {
        f32x4 acc = {0.f, 0.f, 0.f, 0.f};
#pragma unroll
        for (int s = 0; s < 4; s++)
            acc = __builtin_amdgcn_mfma_f32_16x16x32_bf16(a[s], W0[c0][s], acc, 0, 0, 0);
#pragma unroll
        for (int j = 0; j < 4; j++)
            vt[wq][lg * 4 + j][c0 * 16 + lr] = (short)f2bf(ftanh(acc[j] + b0v[c0]));
    }
    {
        bf16x8 av = *(const bf16x8*)&vt[wq][lr][lg * 8];
        f32x4 acc[2];
#pragma unroll
        for (int c0 = 0; c0 < 2; c0++) {
            f32x4 z = {0.f, 0.f, 0.f, 0.f};
            acc[c0] = __builtin_amdgcn_mfma_f32_16x16x32_bf16(av, W1[c0], z, 0, 0, 0);
        }
#pragma unroll
        for (int c0 = 0; c0 < 2; c0++)
#pragma unroll
            for (int j = 0; j < 4; j++)
                vt[wq][lg * 4 + j][c0 * 16 + lr] = (short)f2bf(ftanh(acc[c0][j] + b1v[c0]));
    }
    {
        bf16x8 av = *(const bf16x8*)&vt[wq][lr][lg * 8];
        f32x4 acc[2];
#pragma unroll
        for (int c0 = 0; c0 < 2; c0++) {
            f32x4 z = {0.f, 0.f, 0.f, 0.f};
            acc[c0] = __builtin_amdgcn_mfma_f32_16x16x32_bf16(av, W2[c0], z, 0, 0, 0);
        }
#pragma unroll
        for (int c0 = 0; c0 < 2; c0++)
#pragma unroll
            for (int j = 0; j < 4; j++)
                vt[wq][lg * 4 + j][c0 * 16 + lr] = (short)f2bf(ftanh(acc[c0][j] + b2v[c0]));
    }
    {
        bf16x8 av = *(const bf16x8*)&vt[wq][lr][lg * 8];
        f32x4 z = {0.f, 0.f, 0.f, 0.f};
        f32x4 acc = __builtin_amdgcn_mfma_f32_16x16x32_bf16(av, W3, z, 0, 0, 0);
        if (lr < 7) {
#pragma unroll
            for (int j = 0; j < 4; j++) yt[wq][lg * 4 + j][lr] = acc[j] + b3v;
        }
    }
    __builtin_amdgcn_s_waitcnt(0);
    if (l < 16) {
        float y[7];
#pragma unroll
        for (int j = 0; j < 7; j++) y[j] = yt[wq][l][j];
        float mx = y[0];
#pragma unroll
        for (int j = 1; j < 7; j++) mx = fmaxf(mx, y[j]);
        float se = 0.f;
#pragma unroll
        for (int j = 0; j < 7; j++) se += expf(y[j] - mx);
        float lse = mx + logf(se);
#pragma unroll
        for (int j = 0; j < 7; j++) out[(size_t)(n0 + l) * 7 + j] = y[j] - lse;
    }
}

extern "C" void kernel_launch(void* const* d_in, const int* in_sizes, int n_in,
                              void* d_out, int out_size, void* d_ws, size_t ws_size,
                              hipStream_t stream) {
    const float* x   = (const float*)d_in[0];
    const int*   ei  = (const int*)d_in[1];
    const float* ew  = (const float*)d_in[2];
    const float* cw  = (const float*)d_in[3];
    const float* wih = (const float*)d_in[4];
    const float* whh = (const float*)d_in[5];
    const float* bih = (const float*)d_in[6];
    const float* bhh = (const float*)d_in[7];
    const float* w0 = (const float*)d_in[8];
    const float* b0 = (const float*)d_in[9];
    const float* w1 = (const float*)d_in[10];
    const float* b1 = (const float*)d_in[11];
    const float* w2 = (const float*)d_in[12];
    const float* b2 = (const float*)d_in[13];
    const float* w3 = (const float*)d_in[14];
    const float* b3 = (const float*)d_in[15];
    float* out = (float*)d_out;

    float*    h     = (float*)d_ws;
    ushort_t* hbf0  = (ushort_t*)(h + (size_t)NN * CC);
    ushort_t* hbf1  = hbf0 + (size_t)NN * CC;
    ushort_t* m_bf  = hbf1 + (size_t)NN * CC;
    ushort_t* agg_bf= m_bf + (size_t)NN * CC;
    ushort_t* wx_pk = agg_bf + (size_t)NN * CC;
    ushort_t* wh_pk = wx_pk + 3 * CC * CC;
    ushort_t* cw_pk = wh_pk + 3 * CC * CC;
    ushort_t* wm_pk = cw_pk + 3 * CC * CC;        // 6656 shorts
    float*    e_w   = (float*)(wm_pk + 6656);
    int*      e_src = (int*)(e_w + NE);
    int*      off   = e_src + NE;                 // NN+1
    int*      deg   = off + (NN + 1);             // NN
    int*      cursor= deg + NN;                   // NN
    int*      bsum  = cursor + NN;                // SCAN_B
    int*      bofs  = bsum + SCAN_B;              // SCAN_B

    const int* src = ei;
    const int* dst = ei + NE;

    k_cvt<<<(NN * CC) / 1024, 256, 0, stream>>>(x, hbf0);
    k_wpack<<<192, 256, 0, stream>>>(wih, wx_pk);
    k_wpack<<<192, 256, 0, stream>>>(whh, wh_pk);
    k_cpack<<<192, 256, 0, stream>>>(cw, cw_pk);
    k_mpack<<<26, 256, 0, stream>>>(w0, w1, w2, w3, wm_pk);

    // CSR build (once per call)
    hipMemsetAsync(deg, 0, NN * sizeof(int), stream);
    k_count<<<(NE + 255) / 256, 256, 0, stream>>>(dst, deg);
    k_scan1<<<SCAN_B, 256, 0, stream>>>(deg, off, bsum);
    k_scan2<<<1, 256, 0, stream>>>(bsum, bofs, off);
    k_scan3<<<SCAN_B, 256, 0, stream>>>(off, bofs, cursor);
    k_fill<<<(NE + 255) / 256, 256, 0, stream>>>(src, dst, ew, cursor, e_src, e_w);

    const int conv_waves = 4 * ((NRG + C_RG - 1) / C_RG);
    const int conv_blk = (conv_waves + 3) / 4;
    const int gru_waves = 8 * ((NRG + G_RG - 1) / G_RG);
    const int gru_blk = (gru_waves + 3) / 4;

    ushort_t* hin = hbf0;
    ushort_t* hout = hbf1;
    for (int l = 0; l < NL; l++) {
        k_conv<<<conv_blk, 256, 0, stream>>>(hin, cw_pk + (size_t)l * CC * CC, m_bf);
        k_agg<<<(NN + 3) / 4, 256, 0, stream>>>(off, e_src, e_w, m_bf, agg_bf);
        k_gru<<<gru_blk, 256, 0, stream>>>(agg_bf, hin, hout,
                                           (l == 0) ? x : h, h, wx_pk, wh_pk, bih, bhh,
                                           (l < NL - 1) ? 1 : 0);
        ushort_t* tmp = hin; hin = hout; hout = tmp;
    }
    k_mlp<<<(NRG + 3) / 4, 256, 0, stream>>>(hin, wm_pk, b0, b1, b2, b3, out);
}

// Round 8
// 328.032 us; speedup vs baseline: 12.7111x; 1.0258x over previous
//
#include <hip/hip_runtime.h>
#include <hip/hip_bf16.h>
#include <math.h>

#define NN 50000
#define NE 600000
#define CC 128
#define NL 3
#define NRG (NN / 16)      // 3125 row-groups
#define C_RG 4             // row-groups per conv wave
#define G_RG 4             // row-groups per gru wave
#define SCAN_B 196         // ceil(NN/256)

typedef __attribute__((ext_vector_type(8))) short bf16x8;
typedef __attribute__((ext_vector_type(4))) float f32x4;
typedef unsigned short ushort_t;
typedef unsigned int uint_t;

__device__ inline ushort_t f2bf(float f) {
    __hip_bfloat16 b = __float2bfloat16(f);
    return *reinterpret_cast<ushort_t*>(&b);
}
__device__ inline float bf2f(ushort_t u) {
    return __uint_as_float(((uint_t)u) << 16);
}
__device__ inline float fsig(float x) {
    return __builtin_amdgcn_rcpf(1.f + __builtin_amdgcn_exp2f(-1.44269504f * x));
}
__device__ inline float ftanh(float x) {
    float e = __builtin_amdgcn_exp2f(2.88539008f * fabsf(x));
    float t = 1.f - 2.f * __builtin_amdgcn_rcpf(e + 1.f);
    return copysignf(t, x);
}

// ---------------- x -> hbf0 (bf16) ----------------
__global__ __launch_bounds__(256) void k_cvt(const float* __restrict__ x,
                                             ushort_t* __restrict__ h_bf) {
    size_t i = (size_t)blockIdx.x * 256 + threadIdx.x;
    float4 v = ((const float4*)x)[i];
    ushort4 u;
    u.x = f2bf(v.x); u.y = f2bf(v.y); u.z = f2bf(v.z); u.w = f2bf(v.w);
    ((ushort4*)h_bf)[i] = u;
}

// ---------------- GRU weights -> packed bf16 fragments ----------------
__global__ __launch_bounds__(256) void k_wpack(const float* __restrict__ W,
                                               ushort_t* __restrict__ pk) {
    int tid = blockIdx.x * 256 + threadIdx.x;    // 49152
    int e = tid & 7;
    int l = (tid >> 3) & 63;
    int s = (tid >> 9) & 3;
    int rest = tid >> 11;                        // c0*3+g
    int g = rest % 3, c0 = rest / 3;
    int row = g * 128 + c0 * 16 + (l & 15);
    int col = s * 32 + (l >> 4) * 8 + e;
    pk[tid] = f2bf(W[row * 128 + col]);
}

// ---------------- conv weights -> packed bf16 fragments (3 layers) ----------------
__global__ __launch_bounds__(256) void k_cpack(const float* __restrict__ cw,
                                               ushort_t* __restrict__ pk) {
    int tid = blockIdx.x * 256 + threadIdx.x;    // 49152
    int e = tid & 7;
    int l = (tid >> 3) & 63;
    int s = (tid >> 9) & 3;
    int rest = tid >> 11;                        // layer*8 + c0
    int c0 = rest & 7, layer = rest >> 3;
    int c = c0 * 16 + (l & 15);
    int k = s * 32 + (l >> 4) * 8 + e;
    pk[tid] = f2bf(cw[layer * 16384 + k * 128 + c]);
}

// ---------------- MLP weights -> packed bf16 fragments ----------------
__global__ __launch_bounds__(256) void k_mpack(const float* __restrict__ w0,
                                               const float* __restrict__ w1,
                                               const float* __restrict__ w2,
                                               const float* __restrict__ w3,
                                               ushort_t* __restrict__ pk) {
    int tid = blockIdx.x * 256 + threadIdx.x;    // 6656
    if (tid >= 6656) return;
    int e = tid & 7;
    int l = (tid >> 3) & 63;
    int lr = l & 15, lg = l >> 4;
    if (tid < 4096) {
        int s = (tid >> 9) & 3;
        int c0 = tid >> 11;
        pk[tid] = f2bf(w0[(c0 * 16 + lr) * 128 + s * 32 + lg * 8 + e]);
    } else if (tid < 5120) {
        int c0 = (tid - 4096) >> 9;
        pk[tid] = f2bf(w1[(c0 * 16 + lr) * 32 + lg * 8 + e]);
    } else if (tid < 6144) {
        int c0 = (tid - 5120) >> 9;
        pk[tid] = f2bf(w2[(c0 * 16 + lr) * 32 + lg * 8 + e]);
    } else {
        pk[tid] = (lr < 7) ? f2bf(w3[lr * 32 + lg * 8 + e]) : (ushort_t)0;
    }
}

// ---------------- CSR build ----------------
__global__ __launch_bounds__(256) void k_count(const int* __restrict__ dst,
                                               int* __restrict__ deg) {
    int e = blockIdx.x * 256 + threadIdx.x;
    if (e < NE) atomicAdd(&deg[dst[e]], 1);
}

__global__ __launch_bounds__(256) void k_scan1(const int* __restrict__ deg,
                                               int* __restrict__ off,
                                               int* __restrict__ bsum) {
    __shared__ int sm[256];
    int t = threadIdx.x, i = blockIdx.x * 256 + t;
    int v = (i < NN) ? deg[i] : 0;
    sm[t] = v;
    __syncthreads();
#pragma unroll
    for (int ofs = 1; ofs < 256; ofs <<= 1) {
        int u = (t >= ofs) ? sm[t - ofs] : 0;
        __syncthreads();
        sm[t] += u;
        __syncthreads();
    }
    if (i < NN) off[i] = sm[t] - v;
    if (t == 255) bsum[blockIdx.x] = sm[255];
}

__global__ __launch_bounds__(256) void k_scan2(const int* __restrict__ bsum,
                                               int* __restrict__ bofs,
                                               int* __restrict__ off) {
    __shared__ int sm[256];
    int t = threadIdx.x;
    int v = (t < SCAN_B) ? bsum[t] : 0;
    sm[t] = v;
    __syncthreads();
#pragma unroll
    for (int ofs = 1; ofs < 256; ofs <<= 1) {
        int u = (t >= ofs) ? sm[t - ofs] : 0;
        __syncthreads();
        sm[t] += u;
        __syncthreads();
    }
    if (t < SCAN_B) bofs[t] = sm[t] - v;
    if (t == 255) off[NN] = sm[255];
}

__global__ __launch_bounds__(256) void k_scan3(int* __restrict__ off,
                                               const int* __restrict__ bofs,
                                               int* __restrict__ cursor) {
    int t = threadIdx.x, i = blockIdx.x * 256 + t;
    if (i < NN) {
        int o = off[i] + bofs[blockIdx.x];
        off[i] = o;
        cursor[i] = o;
    }
}

// ---------------- fill: one 8B packed (src, w) store per edge ----------------
__global__ __launch_bounds__(256) void k_fill(const int* __restrict__ src,
                                              const int* __restrict__ dst,
                                              const float* __restrict__ ew,
                                              int* __restrict__ cursor,
                                              uint2* __restrict__ e_pair) {
    int e = blockIdx.x * 256 + threadIdx.x;
    if (e >= NE) return;
    int d = dst[e];
    int p = atomicAdd(&cursor[d], 1);
    uint2 pr;
    pr.x = (uint_t)src[e];
    pr.y = __float_as_uint(ew[e]);
    e_pair[p] = pr;
}

// ---------------- m_bf = bf16( h_bf @ W ), weight-resident waves ----------------
__global__ __launch_bounds__(256, 2) void k_conv(const ushort_t* __restrict__ h_bf,
                                                 const ushort_t* __restrict__ cw_pk,
                                                 ushort_t* __restrict__ m_bf) {
    int wid = (blockIdx.x * 256 + threadIdx.x) >> 6;
    int l = threadIdx.x & 63;
    int lr = l & 15, lg = l >> 4;
    int c0g = wid & 3;
    int chunk = wid >> 2;

    bf16x8 B[2][4];
    {
        const bf16x8* pw = (const bf16x8*)cw_pk;
#pragma unroll
        for (int p = 0; p < 2; p++)
#pragma unroll
            for (int s = 0; s < 4; s++)
                B[p][s] = pw[(size_t)(((c0g + 4 * p) * 4 + s) * 64) + l];
    }
    int c_lo = c0g * 16 + lr;

    for (int it = 0; it < C_RG; it++) {
        int rg = chunk * C_RG + it;
        if (rg >= NRG) break;
        int n0 = rg * 16;
        const short* ap = (const short*)h_bf + (size_t)(n0 + lr) * CC + lg * 8;
        bf16x8 a[4];
#pragma unroll
        for (int s = 0; s < 4; s++) a[s] = *(const bf16x8*)(ap + s * 32);
        f32x4 acc0 = {0.f,0.f,0.f,0.f}, acc1 = {0.f,0.f,0.f,0.f};
#pragma unroll
        for (int s = 0; s < 4; s++) {
            acc0 = __builtin_amdgcn_mfma_f32_16x16x32_bf16(a[s], B[0][s], acc0, 0, 0, 0);
            acc1 = __builtin_amdgcn_mfma_f32_16x16x32_bf16(a[s], B[1][s], acc1, 0, 0, 0);
        }
#pragma unroll
        for (int j = 0; j < 4; j++) {
            size_t row = (size_t)(n0 + lg * 4 + j) * CC;
            m_bf[row + c_lo] = f2bf(acc0[j]);
            m_bf[row + c_lo + 64] = f2bf(acc1[j]);
        }
    }
}

// ---------------- agg: 2 edges per wave step; lanes 0-31 edge i, 32-63 edge i+1 ----------------
__global__ __launch_bounds__(256) void k_agg(const int* __restrict__ off,
                                             const uint2* __restrict__ e_pair,
                                             const ushort_t* __restrict__ m_bf,
                                             ushort_t* __restrict__ agg_bf) {
    int node = blockIdx.x * 4 + (threadIdx.x >> 6);
    int l = threadIdx.x & 63;
    int half = l >> 5, sl = l & 31;
    if (node >= NN) return;
    int b = off[node], e = off[node + 1];
    const uint2* m2 = (const uint2*)m_bf;   // row = 32 x uint2 (4 bf16 ch per lane)
    float a0 = 0.f, a1 = 0.f, a2 = 0.f, a3 = 0.f;
    int i = b;
    // unrolled: 4 edges (2 per half) in flight
    for (; i + 4 <= e; i += 4) {
        uint2 p0 = e_pair[i + half];
        uint2 p1 = e_pair[i + 2 + half];
        uint2 v0 = m2[(size_t)p0.x * 32 + sl];
        uint2 v1 = m2[(size_t)p1.x * 32 + sl];
        float w0 = __uint_as_float(p0.y), w1 = __uint_as_float(p1.y);
        a0 += w0 * bf2f((ushort_t)(v0.x & 0xffffu)) + w1 * bf2f((ushort_t)(v1.x & 0xffffu));
        a1 += w0 * bf2f((ushort_t)(v0.x >> 16))     + w1 * bf2f((ushort_t)(v1.x >> 16));
        a2 += w0 * bf2f((ushort_t)(v0.y & 0xffffu)) + w1 * bf2f((ushort_t)(v1.y & 0xffffu));
        a3 += w0 * bf2f((ushort_t)(v0.y >> 16))     + w1 * bf2f((ushort_t)(v1.y >> 16));
    }
    for (; i < e; i += 2) {
        int idx = i + half;
        uint2 pr = (idx < e) ? e_pair[idx] : make_uint2(0u, 0u);
        uint2 v = m2[(size_t)pr.x * 32 + sl];
        float w = __uint_as_float(pr.y);
        a0 += w * bf2f((ushort_t)(v.x & 0xffffu));
        a1 += w * bf2f((ushort_t)(v.x >> 16));
        a2 += w * bf2f((ushort_t)(v.y & 0xffffu));
        a3 += w * bf2f((ushort_t)(v.y >> 16));
    }
    // combine the two half-wave partial sums
    a0 += __shfl_xor(a0, 32);
    a1 += __shfl_xor(a1, 32);
    a2 += __shfl_xor(a2, 32);
    a3 += __shfl_xor(a3, 32);
    if (half == 0) {
        uint2 p;
        p.x = (uint_t)f2bf(a0) | ((uint_t)f2bf(a1) << 16);
        p.y = (uint_t)f2bf(a2) | ((uint_t)f2bf(a3) << 16);
        ((uint2*)agg_bf)[(size_t)node * 32 + sl] = p;
    }
}

// ---------------- fused GRU cell, weight-resident waves, bf16 carry ----------------
__global__ __launch_bounds__(256, 2) void k_gru(const ushort_t* __restrict__ agg_bf,
                                                const ushort_t* __restrict__ hbf_in,
                                                ushort_t* __restrict__ hbf_out,
                                                const ushort_t* __restrict__ wx_pk,
                                                const ushort_t* __restrict__ wh_pk,
                                                const float* __restrict__ b_ih,
                                                const float* __restrict__ b_hh) {
    int wid = (blockIdx.x * 256 + threadIdx.x) >> 6;
    int l = threadIdx.x & 63;
    int c0 = wid & 7;
    int chunk = wid >> 3;
    int lr = l & 15, lg = l >> 4;

    bf16x8 BX[12], BH[12];
    {
        const bf16x8* px = (const bf16x8*)wx_pk + (size_t)c0 * 12 * 64 + l;
        const bf16x8* ph = (const bf16x8*)wh_pk + (size_t)c0 * 12 * 64 + l;
#pragma unroll
        for (int f = 0; f < 12; f++) { BX[f] = px[f * 64]; BH[f] = ph[f * 64]; }
    }
    int c = c0 * 16 + lr;
    float bxr = b_ih[c], bxz = b_ih[128 + c], bxn = b_ih[256 + c];
    float bhr = b_hh[c], bhz = b_hh[128 + c], bhn = b_hh[256 + c];

    for (int it = 0; it < G_RG; it++) {
        int rg = chunk * G_RG + it;
        if (rg >= NRG) break;
        int n0 = rg * 16;
        const short* ap = (const short*)agg_bf + (size_t)(n0 + lr) * CC + lg * 8;
        const short* hp = (const short*)hbf_in + (size_t)(n0 + lr) * CC + lg * 8;
        bf16x8 a[4], hf[4];
#pragma unroll
        for (int s = 0; s < 4; s++) {
            a[s] = *(const bf16x8*)(ap + s * 32);
            hf[s] = *(const bf16x8*)(hp + s * 32);
        }
        float hv[4];
#pragma unroll
        for (int j = 0; j < 4; j++)
            hv[j] = bf2f(hbf_in[(size_t)(n0 + lg * 4 + j) * CC + c]);   // L1-hot (rows already streamed)

        f32x4 r0 = {0.f,0.f,0.f,0.f}, r1 = {0.f,0.f,0.f,0.f}, r2 = {0.f,0.f,0.f,0.f};
        f32x4 r3 = {0.f,0.f,0.f,0.f}, r4 = {0.f,0.f,0.f,0.f}, r5 = {0.f,0.f,0.f,0.f};
#pragma unroll
        for (int s = 0; s < 4; s++) {
            r0 = __builtin_amdgcn_mfma_f32_16x16x32_bf16(a[s], BX[s], r0, 0, 0, 0);
            r1 = __builtin_amdgcn_mfma_f32_16x16x32_bf16(a[s], BX[4 + s], r1, 0, 0, 0);
            r2 = __builtin_amdgcn_mfma_f32_16x16x32_bf16(a[s], BX[8 + s], r2, 0, 0, 0);
            r3 = __builtin_amdgcn_mfma_f32_16x16x32_bf16(hf[s], BH[s], r3, 0, 0, 0);
            r4 = __builtin_amdgcn_mfma_f32_16x16x32_bf16(hf[s], BH[4 + s], r4, 0, 0, 0);
            r5 = __builtin_amdgcn_mfma_f32_16x16x32_bf16(hf[s], BH[8 + s], r5, 0, 0, 0);
        }
#pragma unroll
        for (int j = 0; j < 4; j++) {
            size_t row = (size_t)(n0 + lg * 4 + j);
            float rg_ = fsig(r0[j] + bxr + r3[j] + bhr);
            float zg = fsig(r1[j] + bxz + r4[j] + bhz);
            float ng = ftanh(r2[j] + bxn + rg_ * (r5[j] + bhn));
            float hn2 = (1.f - zg) * ng + zg * hv[j];
            hbf_out[row * CC + c] = f2bf(hn2);
        }
    }
}

// ---------------- MFMA MLP + log_softmax: wave per 16 rows ----------------
__global__ __launch_bounds__(256, 2) void k_mlp(const ushort_t* __restrict__ hbf,
                                                const ushort_t* __restrict__ wm_pk,
                                                const float* __restrict__ b0,
                                                const float* __restrict__ b1,
                                                const float* __restrict__ b2,
                                                const float* __restrict__ b3,
                                                float* __restrict__ out) {
    __shared__ short vt[4][16][40];
    __shared__ float yt[4][16][8];
    int wid = (blockIdx.x * 256 + threadIdx.x) >> 6;
    int wq = threadIdx.x >> 6;
    int l = threadIdx.x & 63;
    int lr = l & 15, lg = l >> 4;

    bf16x8 W0[2][4], W1[2], W2[2], W3;
    {
        const bf16x8* pw = (const bf16x8*)wm_pk;
#pragma unroll
        for (int c0 = 0; c0 < 2; c0++)
#pragma unroll
            for (int s = 0; s < 4; s++) W0[c0][s] = pw[(c0 * 4 + s) * 64 + l];
#pragma unroll
        for (int c0 = 0; c0 < 2; c0++) {
            W1[c0] = pw[512 + c0 * 64 + l];
            W2[c0] = pw[640 + c0 * 64 + l];
        }
        W3 = pw[768 + l];
    }
    float b0v[2] = {b0[lr], b0[16 + lr]};
    float b1v[2] = {b1[lr], b1[16 + lr]};
    float b2v[2] = {b2[lr], b2[16 + lr]};
    float b3v = (lr < 7) ? b3[lr] : 0.f;

    if (wid >= NRG) return;
    int n0 = wid * 16;

    bf16x8 a[4];
    {
        const short* ap = (const short*)hbf + (size_t)(n0 + lr) * CC + lg * 8;
#pragma unroll
        for (int s = 0; s < 4; s++) a[s] = *(const bf16x8*)(ap + s * 32);
    }
#pragma unroll
    for (int c0 = 0; c0 < 2; c0++) {
        f32x4 acc = {0.f, 0.f, 0.f, 0.f};
#pragma unroll
        for (int s = 0; s < 4; s++)
            acc = __builtin_amdgcn_mfma_f32_16x16x32_bf16(a[s], W0[c0][s], acc, 0, 0, 0);
#pragma unroll
        for (int j = 0; j < 4; j++)
            vt[wq][lg * 4 + j][c0 * 16 + lr] = (short)f2bf(ftanh(acc[j] + b0v[c0]));
    }
    {
        bf16x8 av = *(const bf16x8*)&vt[wq][lr][lg * 8];
        f32x4 acc[2];
#pragma unroll
        for (int c0 = 0; c0 < 2; c0++) {
            f32x4 z = {0.f, 0.f, 0.f, 0.f};
            acc[c0] = __builtin_amdgcn_mfma_f32_16x16x32_bf16(av, W1[c0], z, 0, 0, 0);
        }
#pragma unroll
        for (int c0 = 0; c0 < 2; c0++)
#pragma unroll
            for (int j = 0; j < 4; j++)
                vt[wq][lg * 4 + j][c0 * 16 + lr] = (short)f2bf(ftanh(acc[c0][j] + b1v[c0]));
    }
    {
        bf16x8 av = *(const bf16x8*)&vt[wq][lr][lg * 8];
        f32x4 acc[2];
#pragma unroll
        for (int c0 = 0; c0 < 2; c0++) {
            f32x4 z = {0.f, 0.f, 0.f, 0.f};
            acc[c0] = __builtin_amdgcn_mfma_f32_16x16x32_bf16(av, W2[c0], z, 0, 0, 0);
        }
#pragma unroll
        for (int c0 = 0; c0 < 2; c0++)
#pragma unroll
            for (int j = 0; j < 4; j++)
                vt[wq][lg * 4 + j][c0 * 16 + lr] = (short)f2bf(ftanh(acc[c0][j] + b2v[c0]));
    }
    {
        bf16x8 av = *(const bf16x8*)&vt[wq][lr][lg * 8];
        f32x4 z = {0.f, 0.f, 0.f, 0.f};
        f32x4 acc = __builtin_amdgcn_mfma_f32_16x16x32_bf16(av, W3, z, 0, 0, 0);
        if (lr < 7) {
#pragma unroll
            for (int j = 0; j < 4; j++) yt[wq][lg * 4 + j][lr] = acc[j] + b3v;
        }
    }
    __builtin_amdgcn_s_waitcnt(0);
    if (l < 16) {
        float y[7];
#pragma unroll
        for (int j = 0; j < 7; j++) y[j] = yt[wq][l][j];
        float mx = y[0];
#pragma unroll
        for (int j = 1; j < 7; j++) mx = fmaxf(mx, y[j]);
        float se = 0.f;
#pragma unroll
        for (int j = 0; j < 7; j++) se += expf(y[j] - mx);
        float lse = mx + logf(se);
#pragma unroll
        for (int j = 0; j < 7; j++) out[(size_t)(n0 + l) * 7 + j] = y[j] - lse;
    }
}

extern "C" void kernel_launch(void* const* d_in, const int* in_sizes, int n_in,
                              void* d_out, int out_size, void* d_ws, size_t ws_size,
                              hipStream_t stream) {
    const float* x   = (const float*)d_in[0];
    const int*   ei  = (const int*)d_in[1];
    const float* ew  = (const float*)d_in[2];
    const float* cw  = (const float*)d_in[3];
    const float* wih = (const float*)d_in[4];
    const float* whh = (const float*)d_in[5];
    const float* bih = (const float*)d_in[6];
    const float* bhh = (const float*)d_in[7];
    const float* w0 = (const float*)d_in[8];
    const float* b0 = (const float*)d_in[9];
    const float* w1 = (const float*)d_in[10];
    const float* b1 = (const float*)d_in[11];
    const float* w2 = (const float*)d_in[12];
    const float* b2 = (const float*)d_in[13];
    const float* w3 = (const float*)d_in[14];
    const float* b3 = (const float*)d_in[15];
    float* out = (float*)d_out;

    ushort_t* hbf0  = (ushort_t*)d_ws;                 // NN*CC
    ushort_t* hbf1  = hbf0 + (size_t)NN * CC;
    ushort_t* m_bf  = hbf1 + (size_t)NN * CC;
    ushort_t* agg_bf= m_bf + (size_t)NN * CC;
    ushort_t* wx_pk = agg_bf + (size_t)NN * CC;        // 49152
    ushort_t* wh_pk = wx_pk + 3 * CC * CC;
    ushort_t* cw_pk = wh_pk + 3 * CC * CC;
    ushort_t* wm_pk = cw_pk + 3 * CC * CC;             // 6656
    uint2*    e_pair= (uint2*)(wm_pk + 6656);          // NE uint2 (8B aligned: byte offset div by 8)
    int*      off   = (int*)(e_pair + NE);             // NN+1
    int*      deg   = off + (NN + 1);                  // NN
    int*      cursor= deg + NN;                        // NN
    int*      bsum  = cursor + NN;                     // SCAN_B
    int*      bofs  = bsum + SCAN_B;                   // SCAN_B

    const int* src = ei;
    const int* dst = ei + NE;

    k_cvt<<<(NN * CC) / 1024, 256, 0, stream>>>(x, hbf0);
    k_wpack<<<192, 256, 0, stream>>>(wih, wx_pk);
    k_wpack<<<192, 256, 0, stream>>>(whh, wh_pk);
    k_cpack<<<192, 256, 0, stream>>>(cw, cw_pk);
    k_mpack<<<26, 256, 0, stream>>>(w0, w1, w2, w3, wm_pk);

    // CSR build (once per call)
    hipMemsetAsync(deg, 0, NN * sizeof(int), stream);
    k_count<<<(NE + 255) / 256, 256, 0, stream>>>(dst, deg);
    k_scan1<<<SCAN_B, 256, 0, stream>>>(deg, off, bsum);
    k_scan2<<<1, 256, 0, stream>>>(bsum, bofs, off);
    k_scan3<<<SCAN_B, 256, 0, stream>>>(off, bofs, cursor);
    k_fill<<<(NE + 255) / 256, 256, 0, stream>>>(src, dst, ew, cursor, e_pair);

    const int conv_waves = 4 * ((NRG + C_RG - 1) / C_RG);
    const int conv_blk = (conv_waves + 3) / 4;
    const int gru_waves = 8 * ((NRG + G_RG - 1) / G_RG);
    const int gru_blk = (gru_waves + 3) / 4;

    ushort_t* hin = hbf0;
    ushort_t* hout = hbf1;
    for (int l = 0; l < NL; l++) {
        k_conv<<<conv_blk, 256, 0, stream>>>(hin, cw_pk + (size_t)l * CC * CC, m_bf);
        k_agg<<<(NN + 3) / 4, 256, 0, stream>>>(off, e_pair, m_bf, agg_bf);
        k_gru<<<gru_blk, 256, 0, stream>>>(agg_bf, hin, hout, wx_pk, wh_pk, bih, bhh);
        ushort_t* tmp = hin; hin = hout; hout = tmp;
    }
    k_mlp<<<(NRG + 3) / 4, 256, 0, stream>>>(hin, wm_pk, b0, b1, b2, b3, out);
}